// Round 7
// baseline (248.895 us; speedup 1.0000x reference)
//
#include <hip/hip_runtime.h>
#include <hip/hip_bf16.h>

#define N0 4096
#define N1 16384
#define HID 128
#define LAT 64
#define DIM 3
#define NAUG 21
#define JTOT 512    // xl(128) | xr(128) | lins(128) | pe(128)
#define NG 5        // k-groups (K padded 131->160)

typedef __attribute__((ext_vector_type(8))) short bf16x8;
typedef __attribute__((ext_vector_type(4))) float f32x4;

__device__ __constant__ int c_aug[NAUG] = {1,2,3,4,5,6,7,8,9,10,11,12,13,14,
                                           15,16,17,18,19,21,24};

__device__ __forceinline__ unsigned short f2bf(float v) {
    __hip_bfloat16 b = __float2bfloat16(v);
    return *reinterpret_cast<unsigned short*>(&b);
}

// ---------------------------------------------------------------------------
// knn geometry: 64 chunks of 64 x-points; 512-thr knn blocks cover 2048 y
// (YPT=4).  8 blocks per chunk -> 512 knn blocks total, split 32 chunks into
// kernel B (alongside L0) and 32 into kernel C (alongside L1).
// ---------------------------------------------------------------------------
#define KCH 64
#define KCS 64
#define YPT 4
#define KNNB_PER_KERNEL 256    // 32 chunks x 8 xparts

// ---------------------------------------------------------------------------
// prep element space.  NOTE (R6 post-mortem): NO Wt0 buffer -- writing Wt0 in
// prep blocks and reading it in lin0 blocks of the SAME dispatch was an
// unordered cross-block race (absmax 0.082).  lin0 reads lin0W directly
// (R5-verified); the 32KB matrix is L2-hot, so the strided read is cheap.
// ---------------------------------------------------------------------------
#define WSWZ_PER_LAYER 81920   // 160*512
#define H0G4 131072            // (N0/16)*64*8
#define H1G4 524288            // (N1/16)*64*8
#define P_NSWZ (4 * WSWZ_PER_LAYER)          // 327680
#define P_B0 P_NSWZ                          // bias_cat start
#define P_B1 (P_B0 + 4 * JTOT)               // 329728: h0 g4 start
#define P_B2 (P_B1 + H0G4)                   // 460800: h1 g4 start
#define P_B3 (P_B2 + H1G4)                   // 985088 total
#define PREP_BLOCKS (P_B3 / 256)             // 3848
#define LIN0_BLOCKS 2048                     // 4096*128 / 256

// ---------------------------------------------------------------------------
// Kernel A: prep (blocks 0..3847) || lin0 (blocks 3848..5895).  Both read
// only problem inputs -> no intra-kernel dependency.
// ---------------------------------------------------------------------------
__global__ __launch_bounds__(256)
void prep_lin0_kernel(const float* __restrict__ Wl,
                      const float* __restrict__ Wr,
                      const float* __restrict__ We,
                      const float* __restrict__ linsW,
                      const float* __restrict__ bl,
                      const float* __restrict__ br,
                      const float* __restrict__ linsb,
                      const float* __restrict__ lin0W,
                      const float* __restrict__ lin0b,
                      const float* __restrict__ latent,
                      const float* __restrict__ pos0,
                      const float* __restrict__ pos1,
                      unsigned short* __restrict__ Wswz,
                      float* __restrict__ bias_cat,
                      unsigned short* __restrict__ hswz0A,
                      unsigned short* __restrict__ hswz0B,
                      unsigned short* __restrict__ hswz1A,
                      unsigned short* __restrict__ hswz1B) {
    if (blockIdx.x < PREP_BLOCKS) {
        int tid = blockIdx.x * blockDim.x + threadIdx.x;
        if (tid < P_NSWZ) {
            int c = tid / WSWZ_PER_LAYER;
            int r = tid - c * WSWZ_PER_LAYER;    // ((nt*5+g)*64+l)*8+j
            int nt = r / 2560;
            int g  = (r / 512) % 5;
            int l  = (r / 8) % 64;
            int j  = r % 8;
            int k  = g * 32 + (l >> 4) * 8 + j;
            int n  = nt * 16 + (l & 15);
            float v = 0.0f;
            if (k < 131) {
                if (n < 128)      v = Wl[(c * 128 + n) * 131 + k];
                else if (n < 256) v = Wr[(c * 128 + (n - 128)) * 131 + k];
                else if (n < 384) v = linsW[(c * 128 + (n - 256)) * 131 + k];
                else              v = (k >= 128) ? We[(c * 128 + (n - 384)) * 3 + (k - 128)]
                                                 : 0.0f;
            }
            Wswz[tid] = f2bf(v);
        } else if (tid < P_B1) {                 // bias_cat
            int idx = tid - P_B0;
            int c = idx / JTOT;
            int j = idx - c * JTOT;
            float v;
            if (j < 128)        v = bl[c * 128 + j];
            else if (j < 256)   v = br[c * 128 + (j - 128)];
            else if (j < 384)   v = linsb[c * 128 + (j - 256)];
            else                v = 0.0f;
            bias_cat[idx] = v;
        } else if (tid < P_B2) {                 // hswz0 g=4 plane
            int r = tid - P_B1;                  // (mt*64 + l)*8 + j
            int j = r & 7;
            int l = (r >> 3) & 63;
            int mt = r >> 9;
            int row = mt * 16 + (l & 15);
            int k = 128 + (l >> 4) * 8 + j;
            float v = (k < 131) ? pos0[row * 3 + (k - 128)] : 0.0f;
            unsigned short bv = f2bf(v);
            size_t idx = (size_t)((mt * 5 + 4) * 64 + l) * 8 + j;
            hswz0A[idx] = bv;
            hswz0B[idx] = bv;
        } else if (tid < P_B3) {                 // hswz1 g=4 plane
            int r = tid - P_B2;
            int j = r & 7;
            int l = (r >> 3) & 63;
            int mt = r >> 9;
            int row = mt * 16 + (l & 15);
            int k = 128 + (l >> 4) * 8 + j;
            float v = (k < 131) ? pos1[row * 3 + (k - 128)] : 0.0f;
            unsigned short bv = f2bf(v);
            size_t idx = (size_t)((mt * 5 + 4) * 64 + l) * 8 + j;
            hswz1A[idx] = bv;
            hswz1B[idx] = bv;
        }
        return;
    }

    // ---- lin0 (R5-verified): direct lin0W read, no staging buffer ----
    {
        int r = (blockIdx.x - PREP_BLOCKS) * blockDim.x + threadIdx.x;
        int n = r >> 7, j = r & 127;
        const float* lr = &latent[n * 64];
        const float* wr = &lin0W[j * 64];
        float acc = lin0b[j];
#pragma unroll 8
        for (int k = 0; k < 64; ++k) acc += lr[k] * wr[k];
        int g = j >> 5, sub = (j >> 3) & 3, jj = j & 7;
        hswz0A[(size_t)(((n >> 4) * 5 + g) * 64 + sub * 16 + (n & 15)) * 8 + jj] = f2bf(acc);
    }
}

// ---------------------------------------------------------------------------
// Fused GATv2 layer body.  lin result kept in LDS (lin_s) -- no global
// scratch round-trip.  mode 0: f32 x out; mode 1: bf16 A-fragments out;
// mode 2: fused output head.
// ---------------------------------------------------------------------------
#define WROW 40
#define FSTR 132

__device__ __forceinline__ void layer_body(
        const unsigned short* __restrict__ hswz,
        const unsigned short* __restrict__ Wswz,
        const float* __restrict__ bias_cat,
        const float* __restrict__ att,
        const float* __restrict__ bias,
        float* __restrict__ xout,
        unsigned short* __restrict__ hout,
        const float* __restrict__ outW,
        const float* __restrict__ outb,
        const float* __restrict__ pos1,
        int mode, int N, int mt0,
        float (*xls_s)[FSTR], float (*pes_s)[FSTR], float (*xr_s)[FSTR],
        float (*lin_s)[FSTR]) {
    int tid = threadIdx.x;
    int w = tid >> 6;               // 0..7
    int l = tid & 63;
    int quad = l >> 4, lcol = l & 15;
    int n0 = mt0 * 16;
    int MT = N >> 4;

    // ---- GEMM phase ----
    bf16x8 a[3][NG];
#pragma unroll
    for (int i = 0; i < 3; ++i) {
        int mt = mt0 - 2 + i;
        if (mt < 0) mt += MT;
#pragma unroll
        for (int g = 0; g < NG; ++g)
            a[i][g] = *(const bf16x8*)&hswz[(size_t)((mt * NG + g) * 64 + l) * 8];
    }

#pragma unroll
    for (int i = 0; i < 4; ++i) {
        int b = i * 8 + w;          // 0..31, wave-uniform
        int colbase = (b & 7) * 16;
        int ntw, kind;              // kind: 0 xl(3mt) 1 pe(3mt) 2 xr 3 lin
        if (b < 8)       { ntw = b;      kind = 0; }
        else if (b < 16) { ntw = 16 + b; kind = 1; }
        else if (b < 24) { ntw = b - 8;  kind = 2; }
        else             { ntw = b - 8;  kind = 3; }
        bf16x8 bf[NG];
#pragma unroll
        for (int g = 0; g < NG; ++g)
            bf[g] = *(const bf16x8*)&Wswz[(size_t)((ntw * NG + g) * 64 + l) * 8];
        float bv = bias_cat[ntw * 16 + lcol];
        if (kind < 2) {
            float (*dst)[FSTR] = (kind == 0) ? xls_s : pes_s;
#pragma unroll
            for (int m = 0; m < 3; ++m) {
                f32x4 c = {bv, bv, bv, bv};
#pragma unroll
                for (int g = 0; g < NG; ++g)
                    c = __builtin_amdgcn_mfma_f32_16x16x32_bf16(a[m][g], bf[g], c, 0, 0, 0);
                if (m == 0) {
                    if (quad >= 2) {
                        int w0 = (quad - 2) * 4;
#pragma unroll
                        for (int r = 0; r < 4; ++r) dst[w0 + r][colbase + lcol] = c[r];
                    }
                } else {
                    int w0 = m * 16 - 8 + quad * 4;
#pragma unroll
                    for (int r = 0; r < 4; ++r) dst[w0 + r][colbase + lcol] = c[r];
                }
            }
        } else {
            f32x4 c = {bv, bv, bv, bv};
#pragma unroll
            for (int g = 0; g < NG; ++g)
                c = __builtin_amdgcn_mfma_f32_16x16x32_bf16(a[2][g], bf[g], c, 0, 0, 0);
            float (*dst)[FSTR] = (kind == 2) ? xr_s : lin_s;
            int w0 = quad * 4;
#pragma unroll
            for (int r = 0; r < 4; ++r) dst[w0 + r][colbase + lcol] = c[r];
        }
    }
    __syncthreads();

    // ---- Gather phase (max-free softmax; 32 lanes x 4 cols per dst row) ----
    int qh = l >> 5;                // 0..1
    int t = l & 31;                 // 0..31
    int dl = w * 2 + qh;            // 0..15
    int d = n0 + dl;
    int selfrow = dl + 24;
    int i0 = t * 4;

    f32x4 linv = *(const f32x4*)&lin_s[dl][i0];

    float att4[4], base[4], xld[4], pesum[4], o[4];
    {
        f32x4 a0 = *(const f32x4*)&att[i0];
        f32x4 r0 = *(const f32x4*)&xr_s[dl][i0];
        f32x4 x0 = *(const f32x4*)&xls_s[selfrow][i0];
        f32x4 p0 = *(const f32x4*)&pes_s[selfrow][i0];
#pragma unroll
        for (int j = 0; j < 4; ++j) {
            att4[j] = a0[j];
            xld[j]  = x0[j];
            base[j] = r0[j] + p0[j];
            pesum[j] = 0.0f;
            o[j] = 0.0f;
        }
    }

    float den = 0.0f;

#pragma unroll
    for (int k = 0; k < NAUG; ++k) {
        int lr = selfrow - c_aug[k];
        float xls[4], pes[4];
        *(f32x4*)&xls[0] = *(const f32x4*)&xls_s[lr][i0];
        *(f32x4*)&pes[0] = *(const f32x4*)&pes_s[lr][i0];
        float p = 0.0f;
#pragma unroll
        for (int j = 0; j < 4; ++j) {
            float mm = xls[j] + base[j] - pes[j];
            mm = mm > 0.0f ? mm : 0.2f * mm;
            p = fmaf(att4[j], mm, p);
            pesum[j] += pes[j];
        }
        p += __shfl_xor(p, 1, 64);
        p += __shfl_xor(p, 2, 64);
        p += __shfl_xor(p, 4, 64);
        p += __shfl_xor(p, 8, 64);
        p += __shfl_xor(p, 16, 64);
        float wgt = __expf(p);
        den += wgt;
#pragma unroll
        for (int j = 0; j < 4; ++j) o[j] = fmaf(wgt, xls[j], o[j]);
    }
    {   // self loop: eattr = ped - mean(pes); m = xld + base - mean
        const float inv21 = 1.0f / 21.0f;
        float p = 0.0f;
#pragma unroll
        for (int j = 0; j < 4; ++j) {
            float mm = xld[j] + base[j] - pesum[j] * inv21;
            mm = mm > 0.0f ? mm : 0.2f * mm;
            p = fmaf(att4[j], mm, p);
        }
        p += __shfl_xor(p, 1, 64);
        p += __shfl_xor(p, 2, 64);
        p += __shfl_xor(p, 4, 64);
        p += __shfl_xor(p, 8, 64);
        p += __shfl_xor(p, 16, 64);
        float wgt = __expf(p);
        den += wgt;
#pragma unroll
        for (int j = 0; j < 4; ++j) o[j] = fmaf(wgt, xld[j], o[j]);
    }

    float inv = 1.0f / (den + 1e-16f);
    float res[4];
    {
        f32x4 b0 = *(const f32x4*)&bias[i0];
#pragma unroll
        for (int j = 0; j < 4; ++j) {
            float v = o[j] * inv + b0[j];
            v = v > 0.0f ? v : __expf(v) - 1.0f;
            res[j] = v + linv[j];
        }
    }

    if (mode == 0) {
        *(f32x4*)&xout[(size_t)d * 128 + i0] = *(f32x4*)&res[0];
    } else if (mode == 1) {
        unsigned short ob[4];
#pragma unroll
        for (int j = 0; j < 4; ++j) ob[j] = f2bf(res[j]);
        int g = i0 >> 5, sub = (i0 >> 3) & 3, jj = i0 & 7;
        *(uint2*)&hout[(size_t)((((d >> 4) * 5 + g) * 64) + sub * 16 + (d & 15)) * 8 + jj]
            = *(uint2*)ob;
    } else {                        // mode 2: fused output head
        float po[3];
#pragma unroll
        for (int o3 = 0; o3 < 3; ++o3) {
            const float* wr = &outW[o3 * 131 + i0];
            float p = res[0] * wr[0];
            p = fmaf(res[1], wr[1], p);
            p = fmaf(res[2], wr[2], p);
            p = fmaf(res[3], wr[3], p);
            p += __shfl_xor(p, 1, 64);
            p += __shfl_xor(p, 2, 64);
            p += __shfl_xor(p, 4, 64);
            p += __shfl_xor(p, 8, 64);
            p += __shfl_xor(p, 16, 64);
            po[o3] = p;
        }
        if (t == 0) {
            float p0 = pos1[d * 3], p1 = pos1[d * 3 + 1], p2 = pos1[d * 3 + 2];
#pragma unroll
            for (int o3 = 0; o3 < 3; ++o3) {
                xout[d * 3 + o3] = po[o3] + outb[o3] + p0 * outW[o3 * 131 + 128]
                                 + p1 * outW[o3 * 131 + 129] + p2 * outW[o3 * 131 + 130];
            }
        }
    }
}

// ---------------------------------------------------------------------------
// Kernel B/C: N0 layer (blocks 0..255) || knn_part half (blocks 256..511).
// L0/L1 use only half the 2-blk/CU capacity; knn (pure VALU) rides the other
// half and co-schedules with the layer's MFMA (separate pipes).  knn output
// (pb) isn't read until the interp kernel -> stream-ordered.
// ---------------------------------------------------------------------------
__global__ __launch_bounds__(512, 2)
void layer_knn_kernel(const unsigned short* __restrict__ hswz,
                      const unsigned short* __restrict__ Wswz,
                      const float* __restrict__ bias_cat,
                      const float* __restrict__ att,
                      const float* __restrict__ bias,
                      float* __restrict__ xout,
                      unsigned short* __restrict__ hout,
                      const float* __restrict__ pos0,
                      const float* __restrict__ pos1,
                      float* __restrict__ pb_d,
                      int* __restrict__ pb_i,
                      int chunk_base, int mode) {
    __shared__ __align__(16) float xls_s[WROW][FSTR];
    __shared__ __align__(16) float pes_s[WROW][FSTR];
    __shared__ __align__(16) float xr_s[16][FSTR];
    __shared__ __align__(16) float lin_s[16][FSTR];

    if (blockIdx.x < (N0 >> 4)) {
        layer_body(hswz, Wswz, bias_cat, att, bias, xout, hout,
                   nullptr, nullptr, nullptr, mode, N0, blockIdx.x,
                   xls_s, pes_s, xr_s, lin_s);
        return;
    }

    // ---- knn_part (512 thr: 2048 y per block vs one 64-x chunk) ----
    int kb = blockIdx.x - (N0 >> 4);     // 0..255
    int chunk = chunk_base + (kb >> 3);
    int xpart = kb & 7;
    int tid = threadIdx.x;
    float4* sx = (float4*)&xls_s[0][0];  // 1KB scratch
    if (tid < KCS) {
        const float* p = &pos0[(chunk * KCS + tid) * 3];
        float x = p[0], y = p[1], z = p[2];
        sx[tid] = make_float4(x, y, z, x * x + y * y + z * z);
    }
    __syncthreads();
    int ybase = xpart * (512 * YPT) + tid;
    float m2y[YPT][3], sy[YPT];
#pragma unroll
    for (int u = 0; u < YPT; ++u) {
        int y = ybase + u * 512;
        float p0 = pos1[y * 3], p1 = pos1[y * 3 + 1], p2 = pos1[y * 3 + 2];
        m2y[u][0] = -2.0f * p0; m2y[u][1] = -2.0f * p1; m2y[u][2] = -2.0f * p2;
        sy[u] = p0 * p0 + p1 * p1 + p2 * p2;
    }
    float bd0[YPT], bd1[YPT], bd2[YPT];
    int   bi0[YPT], bi1[YPT], bi2[YPT];
#pragma unroll
    for (int u = 0; u < YPT; ++u) {
        bd0[u] = 1e30f; bd1[u] = 1e30f; bd2[u] = 1e30f;
        bi0[u] = 0; bi1[u] = 0; bi2[u] = 0;
    }
    int gbase = chunk * KCS;
#pragma unroll 4
    for (int i = 0; i < KCS; i += 4) {
        float4 s[4];
#pragma unroll
        for (int v = 0; v < 4; ++v) s[v] = sx[i + v];
#pragma unroll
        for (int v = 0; v < 4; ++v) {
            int gi = gbase + i + v;
#pragma unroll
            for (int u = 0; u < YPT; ++u) {
                float t = fmaf(m2y[u][0], s[v].x, s[v].w);
                t = fmaf(m2y[u][1], s[v].y, t);
                t = fmaf(m2y[u][2], s[v].z, t);
                t += sy[u];
                bool c0 = t < bd0[u];
                bool c1 = t < bd1[u];
                bool c2 = t < bd2[u];
                float n0 = fminf(bd0[u], t);
                float n1 = __builtin_amdgcn_fmed3f(bd0[u], bd1[u], t);
                float n2 = __builtin_amdgcn_fmed3f(bd1[u], bd2[u], t);
                int j0 = c0 ? gi : bi0[u];
                int j1 = c0 ? bi0[u] : (c1 ? gi : bi1[u]);
                int j2 = c1 ? bi1[u] : (c2 ? gi : bi2[u]);
                bd0[u] = n0; bd1[u] = n1; bd2[u] = n2;
                bi0[u] = j0; bi1[u] = j1; bi2[u] = j2;
            }
        }
    }
#pragma unroll
    for (int u = 0; u < YPT; ++u) {
        int y = ybase + u * 512;
        int base = (chunk * N1 + y) * 3;
        pb_d[base] = bd0[u]; pb_d[base + 1] = bd1[u]; pb_d[base + 2] = bd2[u];
        pb_i[base] = bi0[u]; pb_i[base + 1] = bi1[u]; pb_i[base + 2] = bi2[u];
    }
}

// ---------------------------------------------------------------------------
// Generic layer kernel (L2, L3): grid = N/16 blocks of 512.
// ---------------------------------------------------------------------------
__global__ __launch_bounds__(512, 2)
void fused_layer_kernel(const unsigned short* __restrict__ hswz,
                        const unsigned short* __restrict__ Wswz,
                        const float* __restrict__ bias_cat,
                        const float* __restrict__ att,
                        const float* __restrict__ bias,
                        float* __restrict__ xout,
                        unsigned short* __restrict__ hout,
                        const float* __restrict__ outW,
                        const float* __restrict__ outb,
                        const float* __restrict__ pos1,
                        int mode, int N) {
    __shared__ __align__(16) float xls_s[WROW][FSTR];
    __shared__ __align__(16) float pes_s[WROW][FSTR];
    __shared__ __align__(16) float xr_s[16][FSTR];
    __shared__ __align__(16) float lin_s[16][FSTR];
    layer_body(hswz, Wswz, bias_cat, att, bias, xout, hout,
               outW, outb, pos1, mode, N, blockIdx.x,
               xls_s, pes_s, xr_s, lin_s);
}

// ---------------------------------------------------------------------------
// Kernel D: per-wave knn merge (64 chunks via butterfly reduce) + interp.
// Each lane merges one chunk's top-3, then 6-step shuffle butterfly over
// disjoint subtrees yields the global top-3 in every lane.
// ---------------------------------------------------------------------------
__global__ __launch_bounds__(512)
void interp_kernel(const float* __restrict__ x0,
                   const float* __restrict__ pb_d,
                   const int* __restrict__ pb_i,
                   unsigned short* __restrict__ hswz) {
    __shared__ float  sw[8][3];
    __shared__ int    si[8][3];
    int tid = threadIdx.x;
    int wave = tid >> 6;
    int lane = tid & 63;
    int y = blockIdx.x * 8 + wave;

    float bd0 = 1e30f, bd1 = 1e30f, bd2 = 1e30f;
    int bi0 = 0, bi1 = 0, bi2 = 0;
    {
        int base = (lane * N1 + y) * 3;
#pragma unroll
        for (int t3 = 0; t3 < 3; ++t3) {
            float t = pb_d[base + t3];
            int gi = pb_i[base + t3];
            bool c0 = t < bd0;
            bool c1 = t < bd1;
            bool c2 = t < bd2;
            float n0 = fminf(bd0, t);
            float n1 = __builtin_amdgcn_fmed3f(bd0, bd1, t);
            float n2 = __builtin_amdgcn_fmed3f(bd1, bd2, t);
            int j0 = c0 ? gi : bi0;
            int j1 = c0 ? bi0 : (c1 ? gi : bi1);
            int j2 = c1 ? bi1 : (c2 ? gi : bi2);
            bd0 = n0; bd1 = n1; bd2 = n2;
            bi0 = j0; bi1 = j1; bi2 = j2;
        }
    }
#pragma unroll
    for (int off = 32; off >= 1; off >>= 1) {
        float od0 = __shfl_xor(bd0, off, 64);
        float od1 = __shfl_xor(bd1, off, 64);
        float od2 = __shfl_xor(bd2, off, 64);
        int   oi0 = __shfl_xor(bi0, off, 64);
        int   oi1 = __shfl_xor(bi1, off, 64);
        int   oi2 = __shfl_xor(bi2, off, 64);
        float td[3] = {od0, od1, od2};
        int   ti[3] = {oi0, oi1, oi2};
#pragma unroll
        for (int t3 = 0; t3 < 3; ++t3) {
            float t = td[t3];
            int gi = ti[t3];
            bool c0 = t < bd0;
            bool c1 = t < bd1;
            bool c2 = t < bd2;
            float n0 = fminf(bd0, t);
            float n1 = __builtin_amdgcn_fmed3f(bd0, bd1, t);
            float n2 = __builtin_amdgcn_fmed3f(bd1, bd2, t);
            int j0 = c0 ? gi : bi0;
            int j1 = c0 ? bi0 : (c1 ? gi : bi1);
            int j2 = c1 ? bi1 : (c2 ? gi : bi2);
            bd0 = n0; bd1 = n1; bd2 = n2;
            bi0 = j0; bi1 = j1; bi2 = j2;
        }
    }
    if (lane == 0) {
        sw[wave][0] = 1.0f / fmaxf(bd0, 1e-16f);
        sw[wave][1] = 1.0f / fmaxf(bd1, 1e-16f);
        sw[wave][2] = 1.0f / fmaxf(bd2, 1e-16f);
        si[wave][0] = bi0; si[wave][1] = bi1; si[wave][2] = bi2;
    }
    __syncthreads();

    float w0 = sw[wave][0], w1 = sw[wave][1], w2 = sw[wave][2];
    int j0 = si[wave][0], j1 = si[wave][1], j2 = si[wave][2];
    int i0 = 2 * lane;
    float inv = 1.0f / (w0 + w1 + w2);
    float2 a = *(const float2*)&x0[(size_t)j0 * 128 + i0];
    float2 b = *(const float2*)&x0[(size_t)j1 * 128 + i0];
    float2 c = *(const float2*)&x0[(size_t)j2 * 128 + i0];
    float rx = (w0 * a.x + w1 * b.x + w2 * c.x) * inv;
    float ry = (w0 * a.y + w1 * b.y + w2 * c.y) * inv;
    unsigned int packed = (unsigned int)f2bf(rx) | ((unsigned int)f2bf(ry) << 16);
    int g = i0 >> 5, sub = (i0 >> 3) & 3, jj = i0 & 7;
    size_t idx = (size_t)((((y >> 4) * 5 + g) * 64) + sub * 16 + (y & 15)) * 8 + jj;
    *(unsigned int*)&hswz[idx] = packed;
}

// ---------------------------------------------------------------------------
extern "C" void kernel_launch(void* const* d_in, const int* in_sizes, int n_in,
                              void* d_out, int out_size, void* d_ws, size_t ws_size,
                              hipStream_t stream) {
    (void)in_sizes; (void)n_in; (void)out_size; (void)ws_size;
    const float* latent   = (const float*)d_in[0];
    const float* pos0     = (const float*)d_in[1];
    const float* pos1     = (const float*)d_in[2];
    const float* conv_Wl  = (const float*)d_in[5];
    const float* conv_bl  = (const float*)d_in[6];
    const float* conv_Wr  = (const float*)d_in[7];
    const float* conv_br  = (const float*)d_in[8];
    const float* conv_We  = (const float*)d_in[9];
    const float* conv_att = (const float*)d_in[10];
    const float* conv_bias= (const float*)d_in[11];
    const float* lin0_W   = (const float*)d_in[12];
    const float* lin0_b   = (const float*)d_in[13];
    const float* lins_W   = (const float*)d_in[14];
    const float* lins_b   = (const float*)d_in[15];
    const float* out_W    = (const float*)d_in[16];
    const float* out_b    = (const float*)d_in[17];
    float* out = (float*)d_out;

    char* ws = (char*)d_ws;
    unsigned short* Wswz = (unsigned short*)ws; ws += (size_t)4 * WSWZ_PER_LAYER * 2;
    float* bias_cat = (float*)ws;  ws += (size_t)4 * JTOT * 4;
    unsigned short* hswz0A = (unsigned short*)ws; ws += (size_t)(N0 / 16) * NG * 64 * 8 * 2;
    unsigned short* hswz0B = (unsigned short*)ws; ws += (size_t)(N0 / 16) * NG * 64 * 8 * 2;
    unsigned short* hswz1A = (unsigned short*)ws; ws += (size_t)(N1 / 16) * NG * 64 * 8 * 2;
    unsigned short* hswz1B = (unsigned short*)ws; ws += (size_t)(N1 / 16) * NG * 64 * 8 * 2;
    float* bufA     = (float*)ws;  ws += (size_t)N0 * 128 * 4;
    float* pb_d     = (float*)ws;  ws += (size_t)KCH * N1 * 3 * 4;
    int*   pb_i     = (int*)ws;    ws += (size_t)KCH * N1 * 3 * 4;

    // A: prep (3848) || lin0 (2048)
    prep_lin0_kernel<<<PREP_BLOCKS + LIN0_BLOCKS, 256, 0, stream>>>(
        conv_Wl, conv_Wr, conv_We, lins_W, conv_bl, conv_br, lins_b,
        lin0_W, lin0_b, latent, pos0, pos1,
        Wswz, bias_cat, hswz0A, hswz0B, hswz1A, hswz1B);

    // B: layer 0 (256 blocks, h0A -> h0B) || knn chunks 0..31 (256 blocks)
    layer_knn_kernel<<<N0 / 16 + KNNB_PER_KERNEL, 512, 0, stream>>>(
        hswz0A, Wswz + (size_t)0 * WSWZ_PER_LAYER, bias_cat + 0 * JTOT,
        conv_att + 0 * 128, conv_bias + 0 * 128, nullptr, hswz0B,
        pos0, pos1, pb_d, pb_i, 0, 1);

    // C: layer 1 (h0B -> bufA) || knn chunks 32..63
    layer_knn_kernel<<<N0 / 16 + KNNB_PER_KERNEL, 512, 0, stream>>>(
        hswz0B, Wswz + (size_t)1 * WSWZ_PER_LAYER, bias_cat + 1 * JTOT,
        conv_att + 1 * 128, conv_bias + 1 * 128, bufA, nullptr,
        pos0, pos1, pb_d, pb_i, 32, 0);

    // D: merge-in-wave + interp (bufA -> h1A fragments)
    interp_kernel<<<N1 / 8, 512, 0, stream>>>(bufA, pb_d, pb_i, hswz1A);

    // E: layer 2 (h1A -> h1B)
    fused_layer_kernel<<<N1 / 16, 512, 0, stream>>>(
        hswz1A, Wswz + (size_t)2 * WSWZ_PER_LAYER, bias_cat + 2 * JTOT,
        conv_att + 2 * 128, conv_bias + 2 * 128, nullptr, hswz1B,
        nullptr, nullptr, nullptr, 1, N1);

    // F: layer 3 (h1B -> out, fused output head)
    fused_layer_kernel<<<N1 / 16, 512, 0, stream>>>(
        hswz1B, Wswz + (size_t)3 * WSWZ_PER_LAYER, bias_cat + 3 * JTOT,
        conv_att + 3 * 128, conv_bias + 3 * 128, out, nullptr,
        out_W, out_b, pos1, 2, N1);
}

// Round 8
// 229.745 us; speedup vs baseline: 1.0834x; 1.0834x over previous
//
#include <hip/hip_runtime.h>
#include <hip/hip_bf16.h>

#define N0 4096
#define N1 16384
#define HID 128
#define LAT 64
#define DIM 3
#define NAUG 21
#define JTOT 512    // xl(128) | xr(128) | lins(128) | pe(128)
#define NG 5        // k-groups (K padded 131->160)

typedef __attribute__((ext_vector_type(8))) short bf16x8;
typedef __attribute__((ext_vector_type(4))) float f32x4;

__device__ __constant__ int c_aug[NAUG] = {1,2,3,4,5,6,7,8,9,10,11,12,13,14,
                                           15,16,17,18,19,21,24};

__device__ __forceinline__ unsigned short f2bf(float v) {
    __hip_bfloat16 b = __float2bfloat16(v);
    return *reinterpret_cast<unsigned short*>(&b);
}

// ---------------------------------------------------------------------------
// knn geometry (R8): 16 chunks x 256 x-points (was 64 x 64).  Same 67M exact
// f32 distance evals; pb partial buffer shrinks 50MB -> 12.6MB and merge
// loop 192 -> 48 entries.  knn lives in kernel A beside prep: knn is
// VALU-bound, prep is memory-bound -- complementary pipes (R7 lesson: beside
// the VALU-heavy layer kernels it serializes instead).
// ---------------------------------------------------------------------------
#define KCH 16
#define KCS 256
#define YPT 4
#define KNN_BLOCKS 256         // 16 chunks x 16 y-parts (256 thr, 1024 y each)

// ---------------------------------------------------------------------------
// prep element space (incl. Wt0: written in A, read by lin0 in B --
// cross-dispatch, stream-ordered; NEVER same-dispatch (R6 race))
// ---------------------------------------------------------------------------
#define WSWZ_PER_LAYER 81920   // 160*512
#define H0G4 131072            // (N0/16)*64*8
#define H1G4 524288            // (N1/16)*64*8
#define P_NSWZ (4 * WSWZ_PER_LAYER)          // 327680
#define P_B0 P_NSWZ                          // bias_cat start
#define P_B1 (P_B0 + 4 * JTOT)               // Wt0 start
#define P_B2 (P_B1 + 64 * 128)               // h0 g4 start
#define P_B3 (P_B2 + H0G4)                   // h1 g4 start
#define P_B4 (P_B3 + H1G4)                   // 993280 total
#define PREP_BLOCKS 3880                     // 993280 / 256

__global__ __launch_bounds__(256)
void prep_knn_kernel(const float* __restrict__ Wl,
                     const float* __restrict__ Wr,
                     const float* __restrict__ We,
                     const float* __restrict__ linsW,
                     const float* __restrict__ bl,
                     const float* __restrict__ br,
                     const float* __restrict__ linsb,
                     const float* __restrict__ lin0W,
                     const float* __restrict__ pos0,
                     const float* __restrict__ pos1,
                     unsigned short* __restrict__ Wswz,
                     float* __restrict__ bias_cat,
                     float* __restrict__ Wt0,
                     unsigned short* __restrict__ hswz0A,
                     unsigned short* __restrict__ hswz0B,
                     unsigned short* __restrict__ hswz1A,
                     unsigned short* __restrict__ hswz1B,
                     float* __restrict__ pb_d,
                     int* __restrict__ pb_i) {
    __shared__ float4 sx[KCS];   // knn branch only: 4KB (x, y, z, |x|^2)

    if (blockIdx.x < KNN_BLOCKS) {
        // ---- knn_part: one 256-x chunk vs 1024 y ----
        int tid = threadIdx.x;
        int chunk = blockIdx.x >> 4;     // 0..15
        int xpart = blockIdx.x & 15;     // 0..15
        {
            const float* p = &pos0[(chunk * KCS + tid) * 3];
            float x = p[0], y = p[1], z = p[2];
            sx[tid] = make_float4(x, y, z, x * x + y * y + z * z);
        }
        __syncthreads();
        int ybase = xpart * (256 * YPT) + tid;
        float m2y[YPT][3], sy[YPT];
#pragma unroll
        for (int u = 0; u < YPT; ++u) {
            int y = ybase + u * 256;
            float p0 = pos1[y * 3], p1 = pos1[y * 3 + 1], p2 = pos1[y * 3 + 2];
            m2y[u][0] = -2.0f * p0; m2y[u][1] = -2.0f * p1; m2y[u][2] = -2.0f * p2;
            sy[u] = p0 * p0 + p1 * p1 + p2 * p2;
        }
        float bd0[YPT], bd1[YPT], bd2[YPT];
        int   bi0[YPT], bi1[YPT], bi2[YPT];
#pragma unroll
        for (int u = 0; u < YPT; ++u) {
            bd0[u] = 1e30f; bd1[u] = 1e30f; bd2[u] = 1e30f;
            bi0[u] = 0; bi1[u] = 0; bi2[u] = 0;
        }
        int gbase = chunk * KCS;
#pragma unroll 4
        for (int i = 0; i < KCS; i += 4) {
            float4 s[4];
#pragma unroll
            for (int v = 0; v < 4; ++v) s[v] = sx[i + v];
#pragma unroll
            for (int v = 0; v < 4; ++v) {
                int gi = gbase + i + v;
#pragma unroll
                for (int u = 0; u < YPT; ++u) {
                    float t = fmaf(m2y[u][0], s[v].x, s[v].w);
                    t = fmaf(m2y[u][1], s[v].y, t);
                    t = fmaf(m2y[u][2], s[v].z, t);
                    t += sy[u];
                    bool c0 = t < bd0[u];
                    bool c1 = t < bd1[u];
                    bool c2 = t < bd2[u];
                    float n0 = fminf(bd0[u], t);
                    float n1 = __builtin_amdgcn_fmed3f(bd0[u], bd1[u], t);
                    float n2 = __builtin_amdgcn_fmed3f(bd1[u], bd2[u], t);
                    int j0 = c0 ? gi : bi0[u];
                    int j1 = c0 ? bi0[u] : (c1 ? gi : bi1[u]);
                    int j2 = c1 ? bi1[u] : (c2 ? gi : bi2[u]);
                    bd0[u] = n0; bd1[u] = n1; bd2[u] = n2;
                    bi0[u] = j0; bi1[u] = j1; bi2[u] = j2;
                }
            }
        }
#pragma unroll
        for (int u = 0; u < YPT; ++u) {
            int y = ybase + u * 256;
            int base = (chunk * N1 + y) * 3;
            pb_d[base] = bd0[u]; pb_d[base + 1] = bd1[u]; pb_d[base + 2] = bd2[u];
            pb_i[base] = bi0[u]; pb_i[base + 1] = bi1[u]; pb_i[base + 2] = bi2[u];
        }
        return;
    }

    // ---- prep ----
    int tid = (blockIdx.x - KNN_BLOCKS) * blockDim.x + threadIdx.x;
    if (tid < P_NSWZ) {
        int c = tid / WSWZ_PER_LAYER;
        int r = tid - c * WSWZ_PER_LAYER;    // ((nt*5+g)*64+l)*8+j
        int nt = r / 2560;
        int g  = (r / 512) % 5;
        int l  = (r / 8) % 64;
        int j  = r % 8;
        int k  = g * 32 + (l >> 4) * 8 + j;
        int n  = nt * 16 + (l & 15);
        float v = 0.0f;
        if (k < 131) {
            if (n < 128)      v = Wl[(c * 128 + n) * 131 + k];
            else if (n < 256) v = Wr[(c * 128 + (n - 128)) * 131 + k];
            else if (n < 384) v = linsW[(c * 128 + (n - 256)) * 131 + k];
            else              v = (k >= 128) ? We[(c * 128 + (n - 384)) * 3 + (k - 128)]
                                             : 0.0f;
        }
        Wswz[tid] = f2bf(v);
    } else if (tid < P_B1) {                 // bias_cat
        int idx = tid - P_B0;
        int c = idx / JTOT;
        int j = idx - c * JTOT;
        float v;
        if (j < 128)        v = bl[c * 128 + j];
        else if (j < 256)   v = br[c * 128 + (j - 128)];
        else if (j < 384)   v = linsb[c * 128 + (j - 256)];
        else                v = 0.0f;
        bias_cat[idx] = v;
    } else if (tid < P_B2) {                 // Wt0 (read by lin0 in kernel B)
        int idx = tid - P_B1;
        int k = idx / 128;
        int j = idx - k * 128;
        Wt0[idx] = lin0W[j * 64 + k];
    } else if (tid < P_B3) {                 // hswz0 g=4 plane
        int r = tid - P_B2;                  // (mt*64 + l)*8 + j
        int j = r & 7;
        int l = (r >> 3) & 63;
        int mt = r >> 9;
        int row = mt * 16 + (l & 15);
        int k = 128 + (l >> 4) * 8 + j;
        float v = (k < 131) ? pos0[row * 3 + (k - 128)] : 0.0f;
        unsigned short bv = f2bf(v);
        size_t idx = (size_t)((mt * 5 + 4) * 64 + l) * 8 + j;
        hswz0A[idx] = bv;
        hswz0B[idx] = bv;
    } else if (tid < P_B4) {                 // hswz1 g=4 plane
        int r = tid - P_B3;
        int j = r & 7;
        int l = (r >> 3) & 63;
        int mt = r >> 9;
        int row = mt * 16 + (l & 15);
        int k = 128 + (l >> 4) * 8 + j;
        float v = (k < 131) ? pos1[row * 3 + (k - 128)] : 0.0f;
        unsigned short bv = f2bf(v);
        size_t idx = (size_t)((mt * 5 + 4) * 64 + l) * 8 + j;
        hswz1A[idx] = bv;
        hswz1B[idx] = bv;
    }
}

// ---------------------------------------------------------------------------
// Kernel B: knn_merge (blocks 0..127) || lin0 (blocks 128..4223).
// merge reads pb from A (stream-ordered); lin0 reads Wt0 from A (ordered).
// ---------------------------------------------------------------------------
#define MERGE_BLOCKS 128       // 16384 / 128

__global__ __launch_bounds__(128)
void lin0_merge_kernel(const float* __restrict__ latent,
                       const float* __restrict__ Wt0,
                       const float* __restrict__ b,
                       unsigned short* __restrict__ hswz0,
                       const float* __restrict__ pb_d,
                       const int* __restrict__ pb_i,
                       int* __restrict__ knn_idx,
                       float* __restrict__ knn_w) {
    __shared__ float lrow[64];

    if (blockIdx.x < MERGE_BLOCKS) {
        // ---- knn_merge: 16 chunks x 3 entries ----
        int y = blockIdx.x * 128 + threadIdx.x;
        float bd0 = 1e30f, bd1 = 1e30f, bd2 = 1e30f;
        int bi0 = 0, bi1 = 0, bi2 = 0;
        for (int c = 0; c < KCH; ++c) {
            int base = (c * N1 + y) * 3;
#pragma unroll
            for (int t3 = 0; t3 < 3; ++t3) {
                float t = pb_d[base + t3];
                int gi = pb_i[base + t3];
                bool c0 = t < bd0;
                bool c1 = t < bd1;
                bool c2 = t < bd2;
                float n0 = fminf(bd0, t);
                float n1 = __builtin_amdgcn_fmed3f(bd0, bd1, t);
                float n2 = __builtin_amdgcn_fmed3f(bd1, bd2, t);
                int j0 = c0 ? gi : bi0;
                int j1 = c0 ? bi0 : (c1 ? gi : bi1);
                int j2 = c1 ? bi1 : (c2 ? gi : bi2);
                bd0 = n0; bd1 = n1; bd2 = n2;
                bi0 = j0; bi1 = j1; bi2 = j2;
            }
        }
        knn_idx[y * 3]     = bi0;
        knn_idx[y * 3 + 1] = bi1;
        knn_idx[y * 3 + 2] = bi2;
        knn_w[y * 3]     = 1.0f / fmaxf(bd0, 1e-16f);
        knn_w[y * 3 + 1] = 1.0f / fmaxf(bd1, 1e-16f);
        knn_w[y * 3 + 2] = 1.0f / fmaxf(bd2, 1e-16f);
        return;
    }

    // ---- lin0 ----
    int n = blockIdx.x - MERGE_BLOCKS;
    int j = threadIdx.x;
    if (j < 64) lrow[j] = latent[n * 64 + j];
    __syncthreads();
    float acc = b[j];
#pragma unroll 8
    for (int k = 0; k < 64; ++k) acc += lrow[k] * Wt0[k * 128 + j];
    int g = j >> 5, sub = (j >> 3) & 3, jj = j & 7;
    hswz0[(size_t)(((n >> 4) * 5 + g) * 64 + sub * 16 + (n & 15)) * 8 + jj] = f2bf(acc);
}

// ---------------------------------------------------------------------------
// Fused GATv2 layer body.  lin result in LDS (lin_s, R7-validated) -- no
// global scratch round-trip.  mode 0: f32 x out; mode 1: bf16 A-fragments;
// mode 2: fused output head.
// ---------------------------------------------------------------------------
#define WROW 40
#define FSTR 132

__device__ __forceinline__ void layer_body(
        const unsigned short* __restrict__ hswz,
        const unsigned short* __restrict__ Wswz,
        const float* __restrict__ bias_cat,
        const float* __restrict__ att,
        const float* __restrict__ bias,
        float* __restrict__ xout,
        unsigned short* __restrict__ hout,
        const float* __restrict__ outW,
        const float* __restrict__ outb,
        const float* __restrict__ pos1,
        int mode, int N, int mt0,
        float (*xls_s)[FSTR], float (*pes_s)[FSTR], float (*xr_s)[FSTR],
        float (*lin_s)[FSTR]) {
    int tid = threadIdx.x;
    int w = tid >> 6;               // 0..7
    int l = tid & 63;
    int quad = l >> 4, lcol = l & 15;
    int n0 = mt0 * 16;
    int MT = N >> 4;

    // ---- GEMM phase ----
    bf16x8 a[3][NG];
#pragma unroll
    for (int i = 0; i < 3; ++i) {
        int mt = mt0 - 2 + i;
        if (mt < 0) mt += MT;
#pragma unroll
        for (int g = 0; g < NG; ++g)
            a[i][g] = *(const bf16x8*)&hswz[(size_t)((mt * NG + g) * 64 + l) * 8];
    }

#pragma unroll
    for (int i = 0; i < 4; ++i) {
        int b = i * 8 + w;          // 0..31, wave-uniform
        int colbase = (b & 7) * 16;
        int ntw, kind;              // kind: 0 xl(3mt) 1 pe(3mt) 2 xr 3 lin
        if (b < 8)       { ntw = b;      kind = 0; }
        else if (b < 16) { ntw = 16 + b; kind = 1; }
        else if (b < 24) { ntw = b - 8;  kind = 2; }
        else             { ntw = b - 8;  kind = 3; }
        bf16x8 bf[NG];
#pragma unroll
        for (int g = 0; g < NG; ++g)
            bf[g] = *(const bf16x8*)&Wswz[(size_t)((ntw * NG + g) * 64 + l) * 8];
        float bv = bias_cat[ntw * 16 + lcol];
        if (kind < 2) {
            float (*dst)[FSTR] = (kind == 0) ? xls_s : pes_s;
#pragma unroll
            for (int m = 0; m < 3; ++m) {
                f32x4 c = {bv, bv, bv, bv};
#pragma unroll
                for (int g = 0; g < NG; ++g)
                    c = __builtin_amdgcn_mfma_f32_16x16x32_bf16(a[m][g], bf[g], c, 0, 0, 0);
                if (m == 0) {
                    if (quad >= 2) {
                        int w0 = (quad - 2) * 4;
#pragma unroll
                        for (int r = 0; r < 4; ++r) dst[w0 + r][colbase + lcol] = c[r];
                    }
                } else {
                    int w0 = m * 16 - 8 + quad * 4;
#pragma unroll
                    for (int r = 0; r < 4; ++r) dst[w0 + r][colbase + lcol] = c[r];
                }
            }
        } else {
            f32x4 c = {bv, bv, bv, bv};
#pragma unroll
            for (int g = 0; g < NG; ++g)
                c = __builtin_amdgcn_mfma_f32_16x16x32_bf16(a[2][g], bf[g], c, 0, 0, 0);
            float (*dst)[FSTR] = (kind == 2) ? xr_s : lin_s;
            int w0 = quad * 4;
#pragma unroll
            for (int r = 0; r < 4; ++r) dst[w0 + r][colbase + lcol] = c[r];
        }
    }
    __syncthreads();

    // ---- Gather phase (max-free softmax; 32 lanes x 4 cols per dst row) ----
    int qh = l >> 5;                // 0..1
    int t = l & 31;                 // 0..31
    int dl = w * 2 + qh;            // 0..15
    int d = n0 + dl;
    int selfrow = dl + 24;
    int i0 = t * 4;

    f32x4 linv = *(const f32x4*)&lin_s[dl][i0];

    float att4[4], base[4], xld[4], pesum[4], o[4];
    {
        f32x4 a0 = *(const f32x4*)&att[i0];
        f32x4 r0 = *(const f32x4*)&xr_s[dl][i0];
        f32x4 x0 = *(const f32x4*)&xls_s[selfrow][i0];
        f32x4 p0 = *(const f32x4*)&pes_s[selfrow][i0];
#pragma unroll
        for (int j = 0; j < 4; ++j) {
            att4[j] = a0[j];
            xld[j]  = x0[j];
            base[j] = r0[j] + p0[j];
            pesum[j] = 0.0f;
            o[j] = 0.0f;
        }
    }

    float den = 0.0f;

#pragma unroll
    for (int k = 0; k < NAUG; ++k) {
        int lr = selfrow - c_aug[k];
        float xls[4], pes[4];
        *(f32x4*)&xls[0] = *(const f32x4*)&xls_s[lr][i0];
        *(f32x4*)&pes[0] = *(const f32x4*)&pes_s[lr][i0];
        float p = 0.0f;
#pragma unroll
        for (int j = 0; j < 4; ++j) {
            float mm = xls[j] + base[j] - pes[j];
            mm = mm > 0.0f ? mm : 0.2f * mm;
            p = fmaf(att4[j], mm, p);
            pesum[j] += pes[j];
        }
        p += __shfl_xor(p, 1, 64);
        p += __shfl_xor(p, 2, 64);
        p += __shfl_xor(p, 4, 64);
        p += __shfl_xor(p, 8, 64);
        p += __shfl_xor(p, 16, 64);
        float wgt = __expf(p);
        den += wgt;
#pragma unroll
        for (int j = 0; j < 4; ++j) o[j] = fmaf(wgt, xls[j], o[j]);
    }
    {   // self loop: eattr = ped - mean(pes); m = xld + base - mean
        const float inv21 = 1.0f / 21.0f;
        float p = 0.0f;
#pragma unroll
        for (int j = 0; j < 4; ++j) {
            float mm = xld[j] + base[j] - pesum[j] * inv21;
            mm = mm > 0.0f ? mm : 0.2f * mm;
            p = fmaf(att4[j], mm, p);
        }
        p += __shfl_xor(p, 1, 64);
        p += __shfl_xor(p, 2, 64);
        p += __shfl_xor(p, 4, 64);
        p += __shfl_xor(p, 8, 64);
        p += __shfl_xor(p, 16, 64);
        float wgt = __expf(p);
        den += wgt;
#pragma unroll
        for (int j = 0; j < 4; ++j) o[j] = fmaf(wgt, xld[j], o[j]);
    }

    float inv = 1.0f / (den + 1e-16f);
    float res[4];
    {
        f32x4 b0 = *(const f32x4*)&bias[i0];
#pragma unroll
        for (int j = 0; j < 4; ++j) {
            float v = o[j] * inv + b0[j];
            v = v > 0.0f ? v : __expf(v) - 1.0f;
            res[j] = v + linv[j];
        }
    }

    if (mode == 0) {
        *(f32x4*)&xout[(size_t)d * 128 + i0] = *(f32x4*)&res[0];
    } else if (mode == 1) {
        unsigned short ob[4];
#pragma unroll
        for (int j = 0; j < 4; ++j) ob[j] = f2bf(res[j]);
        int g = i0 >> 5, sub = (i0 >> 3) & 3, jj = i0 & 7;
        *(uint2*)&hout[(size_t)((((d >> 4) * 5 + g) * 64) + sub * 16 + (d & 15)) * 8 + jj]
            = *(uint2*)ob;
    } else {                        // mode 2: fused output head
        float po[3];
#pragma unroll
        for (int o3 = 0; o3 < 3; ++o3) {
            const float* wr = &outW[o3 * 131 + i0];
            float p = res[0] * wr[0];
            p = fmaf(res[1], wr[1], p);
            p = fmaf(res[2], wr[2], p);
            p = fmaf(res[3], wr[3], p);
            p += __shfl_xor(p, 1, 64);
            p += __shfl_xor(p, 2, 64);
            p += __shfl_xor(p, 4, 64);
            p += __shfl_xor(p, 8, 64);
            p += __shfl_xor(p, 16, 64);
            po[o3] = p;
        }
        if (t == 0) {
            float p0 = pos1[d * 3], p1 = pos1[d * 3 + 1], p2 = pos1[d * 3 + 2];
#pragma unroll
            for (int o3 = 0; o3 < 3; ++o3) {
                xout[d * 3 + o3] = po[o3] + outb[o3] + p0 * outW[o3 * 131 + 128]
                                 + p1 * outW[o3 * 131 + 129] + p2 * outW[o3 * 131 + 130];
            }
        }
    }
}

__global__ __launch_bounds__(512, 2)
void fused_layer_kernel(const unsigned short* __restrict__ hswz,
                        const unsigned short* __restrict__ Wswz,
                        const float* __restrict__ bias_cat,
                        const float* __restrict__ att,
                        const float* __restrict__ bias,
                        float* __restrict__ xout,
                        unsigned short* __restrict__ hout,
                        const float* __restrict__ outW,
                        const float* __restrict__ outb,
                        const float* __restrict__ pos1,
                        int mode, int N) {
    __shared__ __align__(16) float xls_s[WROW][FSTR];
    __shared__ __align__(16) float pes_s[WROW][FSTR];
    __shared__ __align__(16) float xr_s[16][FSTR];
    __shared__ __align__(16) float lin_s[16][FSTR];
    layer_body(hswz, Wswz, bias_cat, att, bias, xout, hout,
               outW, outb, pos1, mode, N, blockIdx.x,
               xls_s, pes_s, xr_s, lin_s);
}

// ---------------------------------------------------------------------------
// interp: writes bf16 A-fragments for layer-2 GEMM directly.
// ---------------------------------------------------------------------------
__global__ __launch_bounds__(256)
void interp_kernel(const float* __restrict__ x0, const int* __restrict__ knn_idx,
                   const float* __restrict__ knn_w, unsigned short* __restrict__ hswz) {
    int wave = threadIdx.x >> 6;
    int lane = threadIdx.x & 63;
    int y = blockIdx.x * 4 + wave;
    int i0 = 2 * lane;
    float w0 = knn_w[y * 3], w1 = knn_w[y * 3 + 1], w2 = knn_w[y * 3 + 2];
    int j0 = knn_idx[y * 3], j1 = knn_idx[y * 3 + 1], j2 = knn_idx[y * 3 + 2];
    float inv = 1.0f / (w0 + w1 + w2);
    float2 a = *(const float2*)&x0[(size_t)j0 * 128 + i0];
    float2 b = *(const float2*)&x0[(size_t)j1 * 128 + i0];
    float2 c = *(const float2*)&x0[(size_t)j2 * 128 + i0];
    float rx = (w0 * a.x + w1 * b.x + w2 * c.x) * inv;
    float ry = (w0 * a.y + w1 * b.y + w2 * c.y) * inv;
    unsigned int packed = (unsigned int)f2bf(rx) | ((unsigned int)f2bf(ry) << 16);
    int g = i0 >> 5, sub = (i0 >> 3) & 3, jj = i0 & 7;
    size_t idx = (size_t)((((y >> 4) * 5 + g) * 64) + sub * 16 + (y & 15)) * 8 + jj;
    *(unsigned int*)&hswz[idx] = packed;
}

// ---------------------------------------------------------------------------
extern "C" void kernel_launch(void* const* d_in, const int* in_sizes, int n_in,
                              void* d_out, int out_size, void* d_ws, size_t ws_size,
                              hipStream_t stream) {
    (void)in_sizes; (void)n_in; (void)out_size; (void)ws_size;
    const float* latent   = (const float*)d_in[0];
    const float* pos0     = (const float*)d_in[1];
    const float* pos1     = (const float*)d_in[2];
    const float* conv_Wl  = (const float*)d_in[5];
    const float* conv_bl  = (const float*)d_in[6];
    const float* conv_Wr  = (const float*)d_in[7];
    const float* conv_br  = (const float*)d_in[8];
    const float* conv_We  = (const float*)d_in[9];
    const float* conv_att = (const float*)d_in[10];
    const float* conv_bias= (const float*)d_in[11];
    const float* lin0_W   = (const float*)d_in[12];
    const float* lin0_b   = (const float*)d_in[13];
    const float* lins_W   = (const float*)d_in[14];
    const float* lins_b   = (const float*)d_in[15];
    const float* out_W    = (const float*)d_in[16];
    const float* out_b    = (const float*)d_in[17];
    float* out = (float*)d_out;

    char* ws = (char*)d_ws;
    unsigned short* Wswz = (unsigned short*)ws; ws += (size_t)4 * WSWZ_PER_LAYER * 2;
    float* bias_cat = (float*)ws;  ws += (size_t)4 * JTOT * 4;
    float* Wt0      = (float*)ws;  ws += (size_t)64 * 128 * 4;
    unsigned short* hswz0A = (unsigned short*)ws; ws += (size_t)(N0 / 16) * NG * 64 * 8 * 2;
    unsigned short* hswz0B = (unsigned short*)ws; ws += (size_t)(N0 / 16) * NG * 64 * 8 * 2;
    unsigned short* hswz1A = (unsigned short*)ws; ws += (size_t)(N1 / 16) * NG * 64 * 8 * 2;
    unsigned short* hswz1B = (unsigned short*)ws; ws += (size_t)(N1 / 16) * NG * 64 * 8 * 2;
    float* bufA     = (float*)ws;  ws += (size_t)N0 * 128 * 4;
    float* pb_d     = (float*)ws;  ws += (size_t)KCH * N1 * 3 * 4;
    int*   pb_i     = (int*)ws;    ws += (size_t)KCH * N1 * 3 * 4;
    int*   knn_idx  = (int*)ws;    ws += (size_t)N1 * 3 * 4;
    float* knn_w    = (float*)ws;  ws += (size_t)N1 * 3 * 4;

    // A: knn_part (256 blocks, first) || prep (3880 blocks)
    prep_knn_kernel<<<KNN_BLOCKS + PREP_BLOCKS, 256, 0, stream>>>(
        conv_Wl, conv_Wr, conv_We, lins_W, conv_bl, conv_br, lins_b, lin0_W,
        pos0, pos1, Wswz, bias_cat, Wt0, hswz0A, hswz0B, hswz1A, hswz1B,
        pb_d, pb_i);

    // B: knn_merge (128 blocks) || lin0 (4096 blocks)
    lin0_merge_kernel<<<MERGE_BLOCKS + N0, 128, 0, stream>>>(
        latent, Wt0, lin0_b, hswz0A, pb_d, pb_i, knn_idx, knn_w);

    // layer 0: h0A -> h0B (bf16 frags);  layer 1: h0B -> bufA (f32)
    fused_layer_kernel<<<N0 / 16, 512, 0, stream>>>(
        hswz0A, Wswz + (size_t)0 * WSWZ_PER_LAYER, bias_cat + 0 * JTOT,
        conv_att + 0 * 128, conv_bias + 0 * 128, nullptr, hswz0B,
        nullptr, nullptr, nullptr, 1, N0);
    fused_layer_kernel<<<N0 / 16, 512, 0, stream>>>(
        hswz0B, Wswz + (size_t)1 * WSWZ_PER_LAYER, bias_cat + 1 * JTOT,
        conv_att + 1 * 128, conv_bias + 1 * 128, bufA, nullptr,
        nullptr, nullptr, nullptr, 0, N0);

    interp_kernel<<<N1 / 4, 256, 0, stream>>>(bufA, knn_idx, knn_w, hswz1A);

    // layer 2: h1A -> h1B;  layer 3: h1B -> out (fused output head)
    fused_layer_kernel<<<N1 / 16, 512, 0, stream>>>(
        hswz1A, Wswz + (size_t)2 * WSWZ_PER_LAYER, bias_cat + 2 * JTOT,
        conv_att + 2 * 128, conv_bias + 2 * 128, nullptr, hswz1B,
        nullptr, nullptr, nullptr, 1, N1);
    fused_layer_kernel<<<N1 / 16, 512, 0, stream>>>(
        hswz1B, Wswz + (size_t)3 * WSWZ_PER_LAYER, bias_cat + 3 * JTOT,
        conv_att + 3 * 128, conv_bias + 3 * 128, out, nullptr,
        out_W, out_b, pos1, 2, N1);
}

// Round 9
// 215.312 us; speedup vs baseline: 1.1560x; 1.0670x over previous
//
#include <hip/hip_runtime.h>
#include <hip/hip_bf16.h>

#define N0 4096
#define N1 16384
#define HID 128
#define LAT 64
#define DIM 3
#define NAUG 21
#define JTOT 512    // xl(128) | xr(128) | lins(128) | pe(128)
#define NG 5        // k-groups (K padded 131->160)

typedef __attribute__((ext_vector_type(8))) short bf16x8;
typedef __attribute__((ext_vector_type(4))) float f32x4;

__device__ __constant__ int c_aug[NAUG] = {1,2,3,4,5,6,7,8,9,10,11,12,13,14,
                                           15,16,17,18,19,21,24};

__device__ __forceinline__ unsigned short f2bf(float v) {
    __hip_bfloat16 b = __float2bfloat16(v);
    return *reinterpret_cast<unsigned short*>(&b);
}

// ---------------------------------------------------------------------------
// knn geometry (R9): 16 chunks x 256 x-points, 64 y-parts per chunk (YPT=1).
// R8 had 256 knn blocks -> 1 block/CU tail at 13% occupancy, 47us.  1024
// blocks give 4 blocks/CU = 16 waves/CU during the knn tail; same 67M exact
// f32 evals.  Floor ~14us at full VALU issue.
// ---------------------------------------------------------------------------
#define KCH 16
#define KCS 256
#define KNN_XPARTS 64
#define KNN_BLOCKS (KCH * KNN_XPARTS)    // 1024

// ---------------------------------------------------------------------------
// prep element space (incl. Wt0: written in A, read by lin0 in B --
// cross-dispatch, stream-ordered; NEVER same-dispatch (R6 race))
// ---------------------------------------------------------------------------
#define WSWZ_PER_LAYER 81920   // 160*512
#define H0G4 131072            // (N0/16)*64*8
#define H1G4 524288            // (N1/16)*64*8
#define P_NSWZ (4 * WSWZ_PER_LAYER)          // 327680
#define P_B0 P_NSWZ                          // bias_cat start
#define P_B1 (P_B0 + 4 * JTOT)               // Wt0 start
#define P_B2 (P_B1 + 64 * 128)               // h0 g4 start
#define P_B3 (P_B2 + H0G4)                   // h1 g4 start
#define P_B4 (P_B3 + H1G4)                   // 993280 total
#define PREP_BLOCKS 3880                     // 993280 / 256

__global__ __launch_bounds__(256)
void prep_knn_kernel(const float* __restrict__ Wl,
                     const float* __restrict__ Wr,
                     const float* __restrict__ We,
                     const float* __restrict__ linsW,
                     const float* __restrict__ bl,
                     const float* __restrict__ br,
                     const float* __restrict__ linsb,
                     const float* __restrict__ lin0W,
                     const float* __restrict__ pos0,
                     const float* __restrict__ pos1,
                     unsigned short* __restrict__ Wswz,
                     float* __restrict__ bias_cat,
                     float* __restrict__ Wt0,
                     unsigned short* __restrict__ hswz0A,
                     unsigned short* __restrict__ hswz0B,
                     unsigned short* __restrict__ hswz1A,
                     unsigned short* __restrict__ hswz1B,
                     float* __restrict__ pb_d,
                     int* __restrict__ pb_i) {
    __shared__ float4 sx[KCS];   // knn branch only: 4KB (x, y, z, |x|^2)

    if (blockIdx.x < KNN_BLOCKS) {
        // ---- knn_part: one 256-x chunk vs 256 y ----
        int tid = threadIdx.x;
        int chunk = blockIdx.x >> 6;     // 0..15
        int xpart = blockIdx.x & 63;     // 0..63
        {
            const float* p = &pos0[(chunk * KCS + tid) * 3];
            float x = p[0], y = p[1], z = p[2];
            sx[tid] = make_float4(x, y, z, x * x + y * y + z * z);
        }
        __syncthreads();
        int y = xpart * 256 + tid;
        float p0 = pos1[y * 3], p1 = pos1[y * 3 + 1], p2 = pos1[y * 3 + 2];
        float m0 = -2.0f * p0, m1 = -2.0f * p1, m2 = -2.0f * p2;
        float sy = p0 * p0 + p1 * p1 + p2 * p2;
        float bd0 = 1e30f, bd1 = 1e30f, bd2 = 1e30f;
        int bi0 = 0, bi1 = 0, bi2 = 0;
        int gbase = chunk * KCS;
#pragma unroll 4
        for (int i = 0; i < KCS; i += 4) {
            float4 s[4];
#pragma unroll
            for (int v = 0; v < 4; ++v) s[v] = sx[i + v];
#pragma unroll
            for (int v = 0; v < 4; ++v) {
                int gi = gbase + i + v;
                float t = fmaf(m0, s[v].x, s[v].w);
                t = fmaf(m1, s[v].y, t);
                t = fmaf(m2, s[v].z, t);
                t += sy;
                bool c0 = t < bd0;
                bool c1 = t < bd1;
                bool c2 = t < bd2;
                float n0 = fminf(bd0, t);
                float n1 = __builtin_amdgcn_fmed3f(bd0, bd1, t);
                float n2 = __builtin_amdgcn_fmed3f(bd1, bd2, t);
                int j0 = c0 ? gi : bi0;
                int j1 = c0 ? bi0 : (c1 ? gi : bi1);
                int j2 = c1 ? bi1 : (c2 ? gi : bi2);
                bd0 = n0; bd1 = n1; bd2 = n2;
                bi0 = j0; bi1 = j1; bi2 = j2;
            }
        }
        int base = (chunk * N1 + y) * 3;
        pb_d[base] = bd0; pb_d[base + 1] = bd1; pb_d[base + 2] = bd2;
        pb_i[base] = bi0; pb_i[base + 1] = bi1; pb_i[base + 2] = bi2;
        return;
    }

    // ---- prep ----
    int tid = (blockIdx.x - KNN_BLOCKS) * blockDim.x + threadIdx.x;
    if (tid < P_NSWZ) {
        int c = tid / WSWZ_PER_LAYER;
        int r = tid - c * WSWZ_PER_LAYER;    // ((nt*5+g)*64+l)*8+j
        int nt = r / 2560;
        int g  = (r / 512) % 5;
        int l  = (r / 8) % 64;
        int j  = r % 8;
        int k  = g * 32 + (l >> 4) * 8 + j;
        int n  = nt * 16 + (l & 15);
        float v = 0.0f;
        if (k < 131) {
            if (n < 128)      v = Wl[(c * 128 + n) * 131 + k];
            else if (n < 256) v = Wr[(c * 128 + (n - 128)) * 131 + k];
            else if (n < 384) v = linsW[(c * 128 + (n - 256)) * 131 + k];
            else              v = (k >= 128) ? We[(c * 128 + (n - 384)) * 3 + (k - 128)]
                                             : 0.0f;
        }
        Wswz[tid] = f2bf(v);
    } else if (tid < P_B1) {                 // bias_cat
        int idx = tid - P_B0;
        int c = idx / JTOT;
        int j = idx - c * JTOT;
        float v;
        if (j < 128)        v = bl[c * 128 + j];
        else if (j < 256)   v = br[c * 128 + (j - 128)];
        else if (j < 384)   v = linsb[c * 128 + (j - 256)];
        else                v = 0.0f;
        bias_cat[idx] = v;
    } else if (tid < P_B2) {                 // Wt0 (read by lin0 in kernel B)
        int idx = tid - P_B1;
        int k = idx / 128;
        int j = idx - k * 128;
        Wt0[idx] = lin0W[j * 64 + k];
    } else if (tid < P_B3) {                 // hswz0 g=4 plane
        int r = tid - P_B2;                  // (mt*64 + l)*8 + j
        int j = r & 7;
        int l = (r >> 3) & 63;
        int mt = r >> 9;
        int row = mt * 16 + (l & 15);
        int k = 128 + (l >> 4) * 8 + j;
        float v = (k < 131) ? pos0[row * 3 + (k - 128)] : 0.0f;
        unsigned short bv = f2bf(v);
        size_t idx = (size_t)((mt * 5 + 4) * 64 + l) * 8 + j;
        hswz0A[idx] = bv;
        hswz0B[idx] = bv;
    } else if (tid < P_B4) {                 // hswz1 g=4 plane
        int r = tid - P_B3;
        int j = r & 7;
        int l = (r >> 3) & 63;
        int mt = r >> 9;
        int row = mt * 16 + (l & 15);
        int k = 128 + (l >> 4) * 8 + j;
        float v = (k < 131) ? pos1[row * 3 + (k - 128)] : 0.0f;
        unsigned short bv = f2bf(v);
        size_t idx = (size_t)((mt * 5 + 4) * 64 + l) * 8 + j;
        hswz1A[idx] = bv;
        hswz1B[idx] = bv;
    }
}

// ---------------------------------------------------------------------------
// Kernel B: knn_merge (blocks 0..127) || lin0 (blocks 128..4223).
// merge reads pb from A (stream-ordered); lin0 reads Wt0 from A (ordered).
// ---------------------------------------------------------------------------
#define MERGE_BLOCKS 128       // 16384 / 128

__global__ __launch_bounds__(128)
void lin0_merge_kernel(const float* __restrict__ latent,
                       const float* __restrict__ Wt0,
                       const float* __restrict__ b,
                       unsigned short* __restrict__ hswz0,
                       const float* __restrict__ pb_d,
                       const int* __restrict__ pb_i,
                       int* __restrict__ knn_idx,
                       float* __restrict__ knn_w) {
    __shared__ float lrow[64];

    if (blockIdx.x < MERGE_BLOCKS) {
        // ---- knn_merge: 16 chunks x 3 entries ----
        int y = blockIdx.x * 128 + threadIdx.x;
        float bd0 = 1e30f, bd1 = 1e30f, bd2 = 1e30f;
        int bi0 = 0, bi1 = 0, bi2 = 0;
        for (int c = 0; c < KCH; ++c) {
            int base = (c * N1 + y) * 3;
#pragma unroll
            for (int t3 = 0; t3 < 3; ++t3) {
                float t = pb_d[base + t3];
                int gi = pb_i[base + t3];
                bool c0 = t < bd0;
                bool c1 = t < bd1;
                bool c2 = t < bd2;
                float n0 = fminf(bd0, t);
                float n1 = __builtin_amdgcn_fmed3f(bd0, bd1, t);
                float n2 = __builtin_amdgcn_fmed3f(bd1, bd2, t);
                int j0 = c0 ? gi : bi0;
                int j1 = c0 ? bi0 : (c1 ? gi : bi1);
                int j2 = c1 ? bi1 : (c2 ? gi : bi2);
                bd0 = n0; bd1 = n1; bd2 = n2;
                bi0 = j0; bi1 = j1; bi2 = j2;
            }
        }
        knn_idx[y * 3]     = bi0;
        knn_idx[y * 3 + 1] = bi1;
        knn_idx[y * 3 + 2] = bi2;
        knn_w[y * 3]     = 1.0f / fmaxf(bd0, 1e-16f);
        knn_w[y * 3 + 1] = 1.0f / fmaxf(bd1, 1e-16f);
        knn_w[y * 3 + 2] = 1.0f / fmaxf(bd2, 1e-16f);
        return;
    }

    // ---- lin0 ----
    int n = blockIdx.x - MERGE_BLOCKS;
    int j = threadIdx.x;
    if (j < 64) lrow[j] = latent[n * 64 + j];
    __syncthreads();
    float acc = b[j];
#pragma unroll 8
    for (int k = 0; k < 64; ++k) acc += lrow[k] * Wt0[k * 128 + j];
    int g = j >> 5, sub = (j >> 3) & 3, jj = j & 7;
    hswz0[(size_t)(((n >> 4) * 5 + g) * 64 + sub * 16 + (n & 15)) * 8 + jj] = f2bf(acc);
}

// ---------------------------------------------------------------------------
// Fused GATv2 layer body.  lin result in LDS (lin_s, R7-validated) -- no
// global scratch round-trip.  mode 0: f32 x out; mode 1: bf16 A-fragments;
// mode 2: fused output head.
// ---------------------------------------------------------------------------
#define WROW 40
#define FSTR 132

__device__ __forceinline__ void layer_body(
        const unsigned short* __restrict__ hswz,
        const unsigned short* __restrict__ Wswz,
        const float* __restrict__ bias_cat,
        const float* __restrict__ att,
        const float* __restrict__ bias,
        float* __restrict__ xout,
        unsigned short* __restrict__ hout,
        const float* __restrict__ outW,
        const float* __restrict__ outb,
        const float* __restrict__ pos1,
        int mode, int N, int mt0,
        float (*xls_s)[FSTR], float (*pes_s)[FSTR], float (*xr_s)[FSTR],
        float (*lin_s)[FSTR]) {
    int tid = threadIdx.x;
    int w = tid >> 6;               // 0..7
    int l = tid & 63;
    int quad = l >> 4, lcol = l & 15;
    int n0 = mt0 * 16;
    int MT = N >> 4;

    // ---- GEMM phase ----
    bf16x8 a[3][NG];
#pragma unroll
    for (int i = 0; i < 3; ++i) {
        int mt = mt0 - 2 + i;
        if (mt < 0) mt += MT;
#pragma unroll
        for (int g = 0; g < NG; ++g)
            a[i][g] = *(const bf16x8*)&hswz[(size_t)((mt * NG + g) * 64 + l) * 8];
    }

#pragma unroll
    for (int i = 0; i < 4; ++i) {
        int b = i * 8 + w;          // 0..31, wave-uniform
        int colbase = (b & 7) * 16;
        int ntw, kind;              // kind: 0 xl(3mt) 1 pe(3mt) 2 xr 3 lin
        if (b < 8)       { ntw = b;      kind = 0; }
        else if (b < 16) { ntw = 16 + b; kind = 1; }
        else if (b < 24) { ntw = b - 8;  kind = 2; }
        else             { ntw = b - 8;  kind = 3; }
        bf16x8 bf[NG];
#pragma unroll
        for (int g = 0; g < NG; ++g)
            bf[g] = *(const bf16x8*)&Wswz[(size_t)((ntw * NG + g) * 64 + l) * 8];
        float bv = bias_cat[ntw * 16 + lcol];
        if (kind < 2) {
            float (*dst)[FSTR] = (kind == 0) ? xls_s : pes_s;
#pragma unroll
            for (int m = 0; m < 3; ++m) {
                f32x4 c = {bv, bv, bv, bv};
#pragma unroll
                for (int g = 0; g < NG; ++g)
                    c = __builtin_amdgcn_mfma_f32_16x16x32_bf16(a[m][g], bf[g], c, 0, 0, 0);
                if (m == 0) {
                    if (quad >= 2) {
                        int w0 = (quad - 2) * 4;
#pragma unroll
                        for (int r = 0; r < 4; ++r) dst[w0 + r][colbase + lcol] = c[r];
                    }
                } else {
                    int w0 = m * 16 - 8 + quad * 4;
#pragma unroll
                    for (int r = 0; r < 4; ++r) dst[w0 + r][colbase + lcol] = c[r];
                }
            }
        } else {
            f32x4 c = {bv, bv, bv, bv};
#pragma unroll
            for (int g = 0; g < NG; ++g)
                c = __builtin_amdgcn_mfma_f32_16x16x32_bf16(a[2][g], bf[g], c, 0, 0, 0);
            float (*dst)[FSTR] = (kind == 2) ? xr_s : lin_s;
            int w0 = quad * 4;
#pragma unroll
            for (int r = 0; r < 4; ++r) dst[w0 + r][colbase + lcol] = c[r];
        }
    }
    __syncthreads();

    // ---- Gather phase (max-free softmax; 32 lanes x 4 cols per dst row) ----
    int qh = l >> 5;                // 0..1
    int t = l & 31;                 // 0..31
    int dl = w * 2 + qh;            // 0..15
    int d = n0 + dl;
    int selfrow = dl + 24;
    int i0 = t * 4;

    f32x4 linv = *(const f32x4*)&lin_s[dl][i0];

    float att4[4], base[4], xld[4], pesum[4], o[4];
    {
        f32x4 a0 = *(const f32x4*)&att[i0];
        f32x4 r0 = *(const f32x4*)&xr_s[dl][i0];
        f32x4 x0 = *(const f32x4*)&xls_s[selfrow][i0];
        f32x4 p0 = *(const f32x4*)&pes_s[selfrow][i0];
#pragma unroll
        for (int j = 0; j < 4; ++j) {
            att4[j] = a0[j];
            xld[j]  = x0[j];
            base[j] = r0[j] + p0[j];
            pesum[j] = 0.0f;
            o[j] = 0.0f;
        }
    }

    float den = 0.0f;

#pragma unroll
    for (int k = 0; k < NAUG; ++k) {
        int lr = selfrow - c_aug[k];
        float xls[4], pes[4];
        *(f32x4*)&xls[0] = *(const f32x4*)&xls_s[lr][i0];
        *(f32x4*)&pes[0] = *(const f32x4*)&pes_s[lr][i0];
        float p = 0.0f;
#pragma unroll
        for (int j = 0; j < 4; ++j) {
            float mm = xls[j] + base[j] - pes[j];
            mm = mm > 0.0f ? mm : 0.2f * mm;
            p = fmaf(att4[j], mm, p);
            pesum[j] += pes[j];
        }
        p += __shfl_xor(p, 1, 64);
        p += __shfl_xor(p, 2, 64);
        p += __shfl_xor(p, 4, 64);
        p += __shfl_xor(p, 8, 64);
        p += __shfl_xor(p, 16, 64);
        float wgt = __expf(p);
        den += wgt;
#pragma unroll
        for (int j = 0; j < 4; ++j) o[j] = fmaf(wgt, xls[j], o[j]);
    }
    {   // self loop: eattr = ped - mean(pes); m = xld + base - mean
        const float inv21 = 1.0f / 21.0f;
        float p = 0.0f;
#pragma unroll
        for (int j = 0; j < 4; ++j) {
            float mm = xld[j] + base[j] - pesum[j] * inv21;
            mm = mm > 0.0f ? mm : 0.2f * mm;
            p = fmaf(att4[j], mm, p);
        }
        p += __shfl_xor(p, 1, 64);
        p += __shfl_xor(p, 2, 64);
        p += __shfl_xor(p, 4, 64);
        p += __shfl_xor(p, 8, 64);
        p += __shfl_xor(p, 16, 64);
        float wgt = __expf(p);
        den += wgt;
#pragma unroll
        for (int j = 0; j < 4; ++j) o[j] = fmaf(wgt, xld[j], o[j]);
    }

    float inv = 1.0f / (den + 1e-16f);
    float res[4];
    {
        f32x4 b0 = *(const f32x4*)&bias[i0];
#pragma unroll
        for (int j = 0; j < 4; ++j) {
            float v = o[j] * inv + b0[j];
            v = v > 0.0f ? v : __expf(v) - 1.0f;
            res[j] = v + linv[j];
        }
    }

    if (mode == 0) {
        *(f32x4*)&xout[(size_t)d * 128 + i0] = *(f32x4*)&res[0];
    } else if (mode == 1) {
        unsigned short ob[4];
#pragma unroll
        for (int j = 0; j < 4; ++j) ob[j] = f2bf(res[j]);
        int g = i0 >> 5, sub = (i0 >> 3) & 3, jj = i0 & 7;
        *(uint2*)&hout[(size_t)((((d >> 4) * 5 + g) * 64) + sub * 16 + (d & 15)) * 8 + jj]
            = *(uint2*)ob;
    } else {                        // mode 2: fused output head
        float po[3];
#pragma unroll
        for (int o3 = 0; o3 < 3; ++o3) {
            const float* wr = &outW[o3 * 131 + i0];
            float p = res[0] * wr[0];
            p = fmaf(res[1], wr[1], p);
            p = fmaf(res[2], wr[2], p);
            p = fmaf(res[3], wr[3], p);
            p += __shfl_xor(p, 1, 64);
            p += __shfl_xor(p, 2, 64);
            p += __shfl_xor(p, 4, 64);
            p += __shfl_xor(p, 8, 64);
            p += __shfl_xor(p, 16, 64);
            po[o3] = p;
        }
        if (t == 0) {
            float p0 = pos1[d * 3], p1 = pos1[d * 3 + 1], p2 = pos1[d * 3 + 2];
#pragma unroll
            for (int o3 = 0; o3 < 3; ++o3) {
                xout[d * 3 + o3] = po[o3] + outb[o3] + p0 * outW[o3 * 131 + 128]
                                 + p1 * outW[o3 * 131 + 129] + p2 * outW[o3 * 131 + 130];
            }
        }
    }
}

__global__ __launch_bounds__(512, 2)
void fused_layer_kernel(const unsigned short* __restrict__ hswz,
                        const unsigned short* __restrict__ Wswz,
                        const float* __restrict__ bias_cat,
                        const float* __restrict__ att,
                        const float* __restrict__ bias,
                        float* __restrict__ xout,
                        unsigned short* __restrict__ hout,
                        const float* __restrict__ outW,
                        const float* __restrict__ outb,
                        const float* __restrict__ pos1,
                        int mode, int N) {
    __shared__ __align__(16) float xls_s[WROW][FSTR];
    __shared__ __align__(16) float pes_s[WROW][FSTR];
    __shared__ __align__(16) float xr_s[16][FSTR];
    __shared__ __align__(16) float lin_s[16][FSTR];
    layer_body(hswz, Wswz, bias_cat, att, bias, xout, hout,
               outW, outb, pos1, mode, N, blockIdx.x,
               xls_s, pes_s, xr_s, lin_s);
}

// ---------------------------------------------------------------------------
// interp: writes bf16 A-fragments for layer-2 GEMM directly.
// ---------------------------------------------------------------------------
__global__ __launch_bounds__(256)
void interp_kernel(const float* __restrict__ x0, const int* __restrict__ knn_idx,
                   const float* __restrict__ knn_w, unsigned short* __restrict__ hswz) {
    int wave = threadIdx.x >> 6;
    int lane = threadIdx.x & 63;
    int y = blockIdx.x * 4 + wave;
    int i0 = 2 * lane;
    float w0 = knn_w[y * 3], w1 = knn_w[y * 3 + 1], w2 = knn_w[y * 3 + 2];
    int j0 = knn_idx[y * 3], j1 = knn_idx[y * 3 + 1], j2 = knn_idx[y * 3 + 2];
    float inv = 1.0f / (w0 + w1 + w2);
    float2 a = *(const float2*)&x0[(size_t)j0 * 128 + i0];
    float2 b = *(const float2*)&x0[(size_t)j1 * 128 + i0];
    float2 c = *(const float2*)&x0[(size_t)j2 * 128 + i0];
    float rx = (w0 * a.x + w1 * b.x + w2 * c.x) * inv;
    float ry = (w0 * a.y + w1 * b.y + w2 * c.y) * inv;
    unsigned int packed = (unsigned int)f2bf(rx) | ((unsigned int)f2bf(ry) << 16);
    int g = i0 >> 5, sub = (i0 >> 3) & 3, jj = i0 & 7;
    size_t idx = (size_t)((((y >> 4) * 5 + g) * 64) + sub * 16 + (y & 15)) * 8 + jj;
    *(unsigned int*)&hswz[idx] = packed;
}

// ---------------------------------------------------------------------------
extern "C" void kernel_launch(void* const* d_in, const int* in_sizes, int n_in,
                              void* d_out, int out_size, void* d_ws, size_t ws_size,
                              hipStream_t stream) {
    (void)in_sizes; (void)n_in; (void)out_size; (void)ws_size;
    const float* latent   = (const float*)d_in[0];
    const float* pos0     = (const float*)d_in[1];
    const float* pos1     = (const float*)d_in[2];
    const float* conv_Wl  = (const float*)d_in[5];
    const float* conv_bl  = (const float*)d_in[6];
    const float* conv_Wr  = (const float*)d_in[7];
    const float* conv_br  = (const float*)d_in[8];
    const float* conv_We  = (const float*)d_in[9];
    const float* conv_att = (const float*)d_in[10];
    const float* conv_bias= (const float*)d_in[11];
    const float* lin0_W   = (const float*)d_in[12];
    const float* lin0_b   = (const float*)d_in[13];
    const float* lins_W   = (const float*)d_in[14];
    const float* lins_b   = (const float*)d_in[15];
    const float* out_W    = (const float*)d_in[16];
    const float* out_b    = (const float*)d_in[17];
    float* out = (float*)d_out;

    char* ws = (char*)d_ws;
    unsigned short* Wswz = (unsigned short*)ws; ws += (size_t)4 * WSWZ_PER_LAYER * 2;
    float* bias_cat = (float*)ws;  ws += (size_t)4 * JTOT * 4;
    float* Wt0      = (float*)ws;  ws += (size_t)64 * 128 * 4;
    unsigned short* hswz0A = (unsigned short*)ws; ws += (size_t)(N0 / 16) * NG * 64 * 8 * 2;
    unsigned short* hswz0B = (unsigned short*)ws; ws += (size_t)(N0 / 16) * NG * 64 * 8 * 2;
    unsigned short* hswz1A = (unsigned short*)ws; ws += (size_t)(N1 / 16) * NG * 64 * 8 * 2;
    unsigned short* hswz1B = (unsigned short*)ws; ws += (size_t)(N1 / 16) * NG * 64 * 8 * 2;
    float* bufA     = (float*)ws;  ws += (size_t)N0 * 128 * 4;
    float* pb_d     = (float*)ws;  ws += (size_t)KCH * N1 * 3 * 4;
    int*   pb_i     = (int*)ws;    ws += (size_t)KCH * N1 * 3 * 4;
    int*   knn_idx  = (int*)ws;    ws += (size_t)N1 * 3 * 4;
    float* knn_w    = (float*)ws;  ws += (size_t)N1 * 3 * 4;

    // A: knn_part (1024 blocks, first) || prep (3880 blocks)
    prep_knn_kernel<<<KNN_BLOCKS + PREP_BLOCKS, 256, 0, stream>>>(
        conv_Wl, conv_Wr, conv_We, lins_W, conv_bl, conv_br, lins_b, lin0_W,
        pos0, pos1, Wswz, bias_cat, Wt0, hswz0A, hswz0B, hswz1A, hswz1B,
        pb_d, pb_i);

    // B: knn_merge (128 blocks) || lin0 (4096 blocks)
    lin0_merge_kernel<<<MERGE_BLOCKS + N0, 128, 0, stream>>>(
        latent, Wt0, lin0_b, hswz0A, pb_d, pb_i, knn_idx, knn_w);

    // layer 0: h0A -> h0B (bf16 frags);  layer 1: h0B -> bufA (f32)
    fused_layer_kernel<<<N0 / 16, 512, 0, stream>>>(
        hswz0A, Wswz + (size_t)0 * WSWZ_PER_LAYER, bias_cat + 0 * JTOT,
        conv_att + 0 * 128, conv_bias + 0 * 128, nullptr, hswz0B,
        nullptr, nullptr, nullptr, 1, N0);
    fused_layer_kernel<<<N0 / 16, 512, 0, stream>>>(
        hswz0B, Wswz + (size_t)1 * WSWZ_PER_LAYER, bias_cat + 1 * JTOT,
        conv_att + 1 * 128, conv_bias + 1 * 128, bufA, nullptr,
        nullptr, nullptr, nullptr, 0, N0);

    interp_kernel<<<N1 / 4, 256, 0, stream>>>(bufA, knn_idx, knn_w, hswz1A);

    // layer 2: h1A -> h1B;  layer 3: h1B -> out (fused output head)
    fused_layer_kernel<<<N1 / 16, 512, 0, stream>>>(
        hswz1A, Wswz + (size_t)2 * WSWZ_PER_LAYER, bias_cat + 2 * JTOT,
        conv_att + 2 * 128, conv_bias + 2 * 128, nullptr, hswz1B,
        nullptr, nullptr, nullptr, 1, N1);
    fused_layer_kernel<<<N1 / 16, 512, 0, stream>>>(
        hswz1B, Wswz + (size_t)3 * WSWZ_PER_LAYER, bias_cat + 3 * JTOT,
        conv_att + 3 * 128, conv_bias + 3 * 128, out, nullptr,
        out_W, out_b, pos1, 2, N1);
}

// Round 10
// 203.061 us; speedup vs baseline: 1.2257x; 1.0603x over previous
//
#include <hip/hip_runtime.h>
#include <hip/hip_bf16.h>

#define N0 4096
#define N1 16384
#define HID 128
#define LAT 64
#define DIM 3
#define NAUG 21
#define JTOT 512    // xl(128) | xr(128) | lins(128) | pe(128)
#define NG 5        // k-groups (K padded 131->160)

typedef __attribute__((ext_vector_type(8))) short bf16x8;
typedef __attribute__((ext_vector_type(4))) float f32x4;

__device__ __constant__ int c_aug[NAUG] = {1,2,3,4,5,6,7,8,9,10,11,12,13,14,
                                           15,16,17,18,19,21,24};

__device__ __forceinline__ unsigned short f2bf(float v) {
    __hip_bfloat16 b = __float2bfloat16(v);
    return *reinterpret_cast<unsigned short*>(&b);
}

// DPP-based cross-lane add: p + lane[ctrl-perm(lane)].p  -- VALU pipe, no LDS.
// 0xB1 = quad_perm[1,0,3,2] (xor1); 0x4E = quad_perm[2,3,0,1] (xor2);
// 0x128 = row_ror:8 (rotation by half a 16-lane row == xor8).
template<int CTRL>
__device__ __forceinline__ float dpp_xadd(float p) {
    return p + __int_as_float(__builtin_amdgcn_mov_dpp(
        __float_as_int(p), CTRL, 0xF, 0xF, true));
}

// 32-lane sum: 3 DPP stages (xor1, xor2, xor8) + 2 swizzle stages (xor4, xor16).
__device__ __forceinline__ float reduce32(float p) {
    p = dpp_xadd<0xB1>(p);
    p = dpp_xadd<0x4E>(p);
    p = dpp_xadd<0x128>(p);
    p += __shfl_xor(p, 4, 64);
    p += __shfl_xor(p, 16, 64);
    return p;
}

// ---------------------------------------------------------------------------
// knn geometry (R9): 16 chunks x 256 x-points, 64 y-parts per chunk.
// 1024 knn blocks -> 4 blocks/CU = 16 waves/CU during the knn tail.
// ---------------------------------------------------------------------------
#define KCH 16
#define KCS 256
#define KNN_XPARTS 64
#define KNN_BLOCKS (KCH * KNN_XPARTS)    // 1024

// ---------------------------------------------------------------------------
// prep element space (incl. Wt0: written in A, read by lin0 in B --
// cross-dispatch, stream-ordered; NEVER same-dispatch (R6 race))
// ---------------------------------------------------------------------------
#define WSWZ_PER_LAYER 81920   // 160*512
#define H0G4 131072            // (N0/16)*64*8
#define H1G4 524288            // (N1/16)*64*8
#define P_NSWZ (4 * WSWZ_PER_LAYER)          // 327680
#define P_B0 P_NSWZ                          // bias_cat start
#define P_B1 (P_B0 + 4 * JTOT)               // Wt0 start
#define P_B2 (P_B1 + 64 * 128)               // h0 g4 start
#define P_B3 (P_B2 + H0G4)                   // h1 g4 start
#define P_B4 (P_B3 + H1G4)                   // 993280 total
#define PREP_BLOCKS 3880                     // 993280 / 256

__global__ __launch_bounds__(256)
void prep_knn_kernel(const float* __restrict__ Wl,
                     const float* __restrict__ Wr,
                     const float* __restrict__ We,
                     const float* __restrict__ linsW,
                     const float* __restrict__ bl,
                     const float* __restrict__ br,
                     const float* __restrict__ linsb,
                     const float* __restrict__ lin0W,
                     const float* __restrict__ pos0,
                     const float* __restrict__ pos1,
                     unsigned short* __restrict__ Wswz,
                     float* __restrict__ bias_cat,
                     float* __restrict__ Wt0,
                     unsigned short* __restrict__ hswz0A,
                     unsigned short* __restrict__ hswz0B,
                     unsigned short* __restrict__ hswz1A,
                     unsigned short* __restrict__ hswz1B,
                     float* __restrict__ pb_d,
                     int* __restrict__ pb_i) {
    __shared__ float4 sx[KCS];   // knn branch only: 4KB (x, y, z, |x|^2)

    if (blockIdx.x < KNN_BLOCKS) {
        // ---- knn_part: one 256-x chunk vs 256 y ----
        int tid = threadIdx.x;
        int chunk = blockIdx.x >> 6;     // 0..15
        int xpart = blockIdx.x & 63;     // 0..63
        {
            const float* p = &pos0[(chunk * KCS + tid) * 3];
            float x = p[0], y = p[1], z = p[2];
            sx[tid] = make_float4(x, y, z, x * x + y * y + z * z);
        }
        __syncthreads();
        int y = xpart * 256 + tid;
        float p0 = pos1[y * 3], p1 = pos1[y * 3 + 1], p2 = pos1[y * 3 + 2];
        float m0 = -2.0f * p0, m1 = -2.0f * p1, m2 = -2.0f * p2;
        float sy = p0 * p0 + p1 * p1 + p2 * p2;
        float bd0 = 1e30f, bd1 = 1e30f, bd2 = 1e30f;
        int bi0 = 0, bi1 = 0, bi2 = 0;
        int gbase = chunk * KCS;
#pragma unroll 4
        for (int i = 0; i < KCS; i += 4) {
            float4 s[4];
#pragma unroll
            for (int v = 0; v < 4; ++v) s[v] = sx[i + v];
#pragma unroll
            for (int v = 0; v < 4; ++v) {
                int gi = gbase + i + v;
                float t = fmaf(m0, s[v].x, s[v].w);
                t = fmaf(m1, s[v].y, t);
                t = fmaf(m2, s[v].z, t);
                t += sy;
                bool c0 = t < bd0;
                bool c1 = t < bd1;
                bool c2 = t < bd2;
                float n0 = fminf(bd0, t);
                float n1 = __builtin_amdgcn_fmed3f(bd0, bd1, t);
                float n2 = __builtin_amdgcn_fmed3f(bd1, bd2, t);
                int j0 = c0 ? gi : bi0;
                int j1 = c0 ? bi0 : (c1 ? gi : bi1);
                int j2 = c1 ? bi1 : (c2 ? gi : bi2);
                bd0 = n0; bd1 = n1; bd2 = n2;
                bi0 = j0; bi1 = j1; bi2 = j2;
            }
        }
        int base = (chunk * N1 + y) * 3;
        pb_d[base] = bd0; pb_d[base + 1] = bd1; pb_d[base + 2] = bd2;
        pb_i[base] = bi0; pb_i[base + 1] = bi1; pb_i[base + 2] = bi2;
        return;
    }

    // ---- prep ----
    int tid = (blockIdx.x - KNN_BLOCKS) * blockDim.x + threadIdx.x;
    if (tid < P_NSWZ) {
        int c = tid / WSWZ_PER_LAYER;
        int r = tid - c * WSWZ_PER_LAYER;    // ((nt*5+g)*64+l)*8+j
        int nt = r / 2560;
        int g  = (r / 512) % 5;
        int l  = (r / 8) % 64;
        int j  = r % 8;
        int k  = g * 32 + (l >> 4) * 8 + j;
        int n  = nt * 16 + (l & 15);
        float v = 0.0f;
        if (k < 131) {
            if (n < 128)      v = Wl[(c * 128 + n) * 131 + k];
            else if (n < 256) v = Wr[(c * 128 + (n - 128)) * 131 + k];
            else if (n < 384) v = linsW[(c * 128 + (n - 256)) * 131 + k];
            else              v = (k >= 128) ? We[(c * 128 + (n - 384)) * 3 + (k - 128)]
                                             : 0.0f;
        }
        Wswz[tid] = f2bf(v);
    } else if (tid < P_B1) {                 // bias_cat
        int idx = tid - P_B0;
        int c = idx / JTOT;
        int j = idx - c * JTOT;
        float v;
        if (j < 128)        v = bl[c * 128 + j];
        else if (j < 256)   v = br[c * 128 + (j - 128)];
        else if (j < 384)   v = linsb[c * 128 + (j - 256)];
        else                v = 0.0f;
        bias_cat[idx] = v;
    } else if (tid < P_B2) {                 // Wt0 (read by lin0 in kernel B)
        int idx = tid - P_B1;
        int k = idx / 128;
        int j = idx - k * 128;
        Wt0[idx] = lin0W[j * 64 + k];
    } else if (tid < P_B3) {                 // hswz0 g=4 plane
        int r = tid - P_B2;                  // (mt*64 + l)*8 + j
        int j = r & 7;
        int l = (r >> 3) & 63;
        int mt = r >> 9;
        int row = mt * 16 + (l & 15);
        int k = 128 + (l >> 4) * 8 + j;
        float v = (k < 131) ? pos0[row * 3 + (k - 128)] : 0.0f;
        unsigned short bv = f2bf(v);
        size_t idx = (size_t)((mt * 5 + 4) * 64 + l) * 8 + j;
        hswz0A[idx] = bv;
        hswz0B[idx] = bv;
    } else if (tid < P_B4) {                 // hswz1 g=4 plane
        int r = tid - P_B3;
        int j = r & 7;
        int l = (r >> 3) & 63;
        int mt = r >> 9;
        int row = mt * 16 + (l & 15);
        int k = 128 + (l >> 4) * 8 + j;
        float v = (k < 131) ? pos1[row * 3 + (k - 128)] : 0.0f;
        unsigned short bv = f2bf(v);
        size_t idx = (size_t)((mt * 5 + 4) * 64 + l) * 8 + j;
        hswz1A[idx] = bv;
        hswz1B[idx] = bv;
    }
}

// ---------------------------------------------------------------------------
// Kernel B: knn_merge (blocks 0..127) || lin0 (blocks 128..4223).
// merge reads pb from A (stream-ordered); lin0 reads Wt0 from A (ordered).
// ---------------------------------------------------------------------------
#define MERGE_BLOCKS 128       // 16384 / 128

__global__ __launch_bounds__(128)
void lin0_merge_kernel(const float* __restrict__ latent,
                       const float* __restrict__ Wt0,
                       const float* __restrict__ b,
                       unsigned short* __restrict__ hswz0,
                       const float* __restrict__ pb_d,
                       const int* __restrict__ pb_i,
                       int* __restrict__ knn_idx,
                       float* __restrict__ knn_w) {
    __shared__ float lrow[64];

    if (blockIdx.x < MERGE_BLOCKS) {
        // ---- knn_merge: 16 chunks x 3 entries ----
        int y = blockIdx.x * 128 + threadIdx.x;
        float bd0 = 1e30f, bd1 = 1e30f, bd2 = 1e30f;
        int bi0 = 0, bi1 = 0, bi2 = 0;
        for (int c = 0; c < KCH; ++c) {
            int base = (c * N1 + y) * 3;
#pragma unroll
            for (int t3 = 0; t3 < 3; ++t3) {
                float t = pb_d[base + t3];
                int gi = pb_i[base + t3];
                bool c0 = t < bd0;
                bool c1 = t < bd1;
                bool c2 = t < bd2;
                float n0 = fminf(bd0, t);
                float n1 = __builtin_amdgcn_fmed3f(bd0, bd1, t);
                float n2 = __builtin_amdgcn_fmed3f(bd1, bd2, t);
                int j0 = c0 ? gi : bi0;
                int j1 = c0 ? bi0 : (c1 ? gi : bi1);
                int j2 = c1 ? bi1 : (c2 ? gi : bi2);
                bd0 = n0; bd1 = n1; bd2 = n2;
                bi0 = j0; bi1 = j1; bi2 = j2;
            }
        }
        knn_idx[y * 3]     = bi0;
        knn_idx[y * 3 + 1] = bi1;
        knn_idx[y * 3 + 2] = bi2;
        knn_w[y * 3]     = 1.0f / fmaxf(bd0, 1e-16f);
        knn_w[y * 3 + 1] = 1.0f / fmaxf(bd1, 1e-16f);
        knn_w[y * 3 + 2] = 1.0f / fmaxf(bd2, 1e-16f);
        return;
    }

    // ---- lin0 ----
    int n = blockIdx.x - MERGE_BLOCKS;
    int j = threadIdx.x;
    if (j < 64) lrow[j] = latent[n * 64 + j];
    __syncthreads();
    float acc = b[j];
#pragma unroll 8
    for (int k = 0; k < 64; ++k) acc += lrow[k] * Wt0[k * 128 + j];
    int g = j >> 5, sub = (j >> 3) & 3, jj = j & 7;
    hswz0[(size_t)(((n >> 4) * 5 + g) * 64 + sub * 16 + (n & 15)) * 8 + jj] = f2bf(acc);
}

// ---------------------------------------------------------------------------
// Fused GATv2 layer body.  lin result in LDS (lin_s); gather reduce uses
// 3 DPP stages + 2 swizzle stages (R10: cuts gather LDS ops/iter 7 -> 4).
// mode 0: f32 x out; mode 1: bf16 A-fragments; mode 2: fused output head.
// ---------------------------------------------------------------------------
#define WROW 40
#define FSTR 132

__device__ __forceinline__ void layer_body(
        const unsigned short* __restrict__ hswz,
        const unsigned short* __restrict__ Wswz,
        const float* __restrict__ bias_cat,
        const float* __restrict__ att,
        const float* __restrict__ bias,
        float* __restrict__ xout,
        unsigned short* __restrict__ hout,
        const float* __restrict__ outW,
        const float* __restrict__ outb,
        const float* __restrict__ pos1,
        int mode, int N, int mt0,
        float (*xls_s)[FSTR], float (*pes_s)[FSTR], float (*xr_s)[FSTR],
        float (*lin_s)[FSTR]) {
    int tid = threadIdx.x;
    int w = tid >> 6;               // 0..7
    int l = tid & 63;
    int quad = l >> 4, lcol = l & 15;
    int n0 = mt0 * 16;
    int MT = N >> 4;

    // ---- GEMM phase ----
    bf16x8 a[3][NG];
#pragma unroll
    for (int i = 0; i < 3; ++i) {
        int mt = mt0 - 2 + i;
        if (mt < 0) mt += MT;
#pragma unroll
        for (int g = 0; g < NG; ++g)
            a[i][g] = *(const bf16x8*)&hswz[(size_t)((mt * NG + g) * 64 + l) * 8];
    }

#pragma unroll
    for (int i = 0; i < 4; ++i) {
        int b = i * 8 + w;          // 0..31, wave-uniform
        int colbase = (b & 7) * 16;
        int ntw, kind;              // kind: 0 xl(3mt) 1 pe(3mt) 2 xr 3 lin
        if (b < 8)       { ntw = b;      kind = 0; }
        else if (b < 16) { ntw = 16 + b; kind = 1; }
        else if (b < 24) { ntw = b - 8;  kind = 2; }
        else             { ntw = b - 8;  kind = 3; }
        bf16x8 bf[NG];
#pragma unroll
        for (int g = 0; g < NG; ++g)
            bf[g] = *(const bf16x8*)&Wswz[(size_t)((ntw * NG + g) * 64 + l) * 8];
        float bv = bias_cat[ntw * 16 + lcol];
        if (kind < 2) {
            float (*dst)[FSTR] = (kind == 0) ? xls_s : pes_s;
#pragma unroll
            for (int m = 0; m < 3; ++m) {
                f32x4 c = {bv, bv, bv, bv};
#pragma unroll
                for (int g = 0; g < NG; ++g)
                    c = __builtin_amdgcn_mfma_f32_16x16x32_bf16(a[m][g], bf[g], c, 0, 0, 0);
                if (m == 0) {
                    if (quad >= 2) {
                        int w0 = (quad - 2) * 4;
#pragma unroll
                        for (int r = 0; r < 4; ++r) dst[w0 + r][colbase + lcol] = c[r];
                    }
                } else {
                    int w0 = m * 16 - 8 + quad * 4;
#pragma unroll
                    for (int r = 0; r < 4; ++r) dst[w0 + r][colbase + lcol] = c[r];
                }
            }
        } else {
            f32x4 c = {bv, bv, bv, bv};
#pragma unroll
            for (int g = 0; g < NG; ++g)
                c = __builtin_amdgcn_mfma_f32_16x16x32_bf16(a[2][g], bf[g], c, 0, 0, 0);
            float (*dst)[FSTR] = (kind == 2) ? xr_s : lin_s;
            int w0 = quad * 4;
#pragma unroll
            for (int r = 0; r < 4; ++r) dst[w0 + r][colbase + lcol] = c[r];
        }
    }
    __syncthreads();

    // ---- Gather phase (max-free softmax; 32 lanes x 4 cols per dst row) ----
    int qh = l >> 5;                // 0..1
    int t = l & 31;                 // 0..31
    int dl = w * 2 + qh;            // 0..15
    int d = n0 + dl;
    int selfrow = dl + 24;
    int i0 = t * 4;

    f32x4 linv = *(const f32x4*)&lin_s[dl][i0];

    float att4[4], base[4], xld[4], pesum[4], o[4];
    {
        f32x4 a0 = *(const f32x4*)&att[i0];
        f32x4 r0 = *(const f32x4*)&xr_s[dl][i0];
        f32x4 x0 = *(const f32x4*)&xls_s[selfrow][i0];
        f32x4 p0 = *(const f32x4*)&pes_s[selfrow][i0];
#pragma unroll
        for (int j = 0; j < 4; ++j) {
            att4[j] = a0[j];
            xld[j]  = x0[j];
            base[j] = r0[j] + p0[j];
            pesum[j] = 0.0f;
            o[j] = 0.0f;
        }
    }

    float den = 0.0f;

#pragma unroll
    for (int k = 0; k < NAUG; ++k) {
        int lr = selfrow - c_aug[k];
        float xls[4], pes[4];
        *(f32x4*)&xls[0] = *(const f32x4*)&xls_s[lr][i0];
        *(f32x4*)&pes[0] = *(const f32x4*)&pes_s[lr][i0];
        float p = 0.0f;
#pragma unroll
        for (int j = 0; j < 4; ++j) {
            float mm = xls[j] + base[j] - pes[j];
            mm = mm > 0.0f ? mm : 0.2f * mm;
            p = fmaf(att4[j], mm, p);
            pesum[j] += pes[j];
        }
        p = reduce32(p);
        float wgt = __expf(p);
        den += wgt;
#pragma unroll
        for (int j = 0; j < 4; ++j) o[j] = fmaf(wgt, xls[j], o[j]);
    }
    {   // self loop: eattr = ped - mean(pes); m = xld + base - mean
        const float inv21 = 1.0f / 21.0f;
        float p = 0.0f;
#pragma unroll
        for (int j = 0; j < 4; ++j) {
            float mm = xld[j] + base[j] - pesum[j] * inv21;
            mm = mm > 0.0f ? mm : 0.2f * mm;
            p = fmaf(att4[j], mm, p);
        }
        p = reduce32(p);
        float wgt = __expf(p);
        den += wgt;
#pragma unroll
        for (int j = 0; j < 4; ++j) o[j] = fmaf(wgt, xld[j], o[j]);
    }

    float inv = 1.0f / (den + 1e-16f);
    float res[4];
    {
        f32x4 b0 = *(const f32x4*)&bias[i0];
#pragma unroll
        for (int j = 0; j < 4; ++j) {
            float v = o[j] * inv + b0[j];
            v = v > 0.0f ? v : __expf(v) - 1.0f;
            res[j] = v + linv[j];
        }
    }

    if (mode == 0) {
        *(f32x4*)&xout[(size_t)d * 128 + i0] = *(f32x4*)&res[0];
    } else if (mode == 1) {
        unsigned short ob[4];
#pragma unroll
        for (int j = 0; j < 4; ++j) ob[j] = f2bf(res[j]);
        int g = i0 >> 5, sub = (i0 >> 3) & 3, jj = i0 & 7;
        *(uint2*)&hout[(size_t)((((d >> 4) * 5 + g) * 64) + sub * 16 + (d & 15)) * 8 + jj]
            = *(uint2*)ob;
    } else {                        // mode 2: fused output head
        float po[3];
#pragma unroll
        for (int o3 = 0; o3 < 3; ++o3) {
            const float* wr = &outW[o3 * 131 + i0];
            float p = res[0] * wr[0];
            p = fmaf(res[1], wr[1], p);
            p = fmaf(res[2], wr[2], p);
            p = fmaf(res[3], wr[3], p);
            p = reduce32(p);
            po[o3] = p;
        }
        if (t == 0) {
            float p0 = pos1[d * 3], p1 = pos1[d * 3 + 1], p2 = pos1[d * 3 + 2];
#pragma unroll
            for (int o3 = 0; o3 < 3; ++o3) {
                xout[d * 3 + o3] = po[o3] + outb[o3] + p0 * outW[o3 * 131 + 128]
                                 + p1 * outW[o3 * 131 + 129] + p2 * outW[o3 * 131 + 130];
            }
        }
    }
}

__global__ __launch_bounds__(512, 2)
void fused_layer_kernel(const unsigned short* __restrict__ hswz,
                        const unsigned short* __restrict__ Wswz,
                        const float* __restrict__ bias_cat,
                        const float* __restrict__ att,
                        const float* __restrict__ bias,
                        float* __restrict__ xout,
                        unsigned short* __restrict__ hout,
                        const float* __restrict__ outW,
                        const float* __restrict__ outb,
                        const float* __restrict__ pos1,
                        int mode, int N) {
    __shared__ __align__(16) float xls_s[WROW][FSTR];
    __shared__ __align__(16) float pes_s[WROW][FSTR];
    __shared__ __align__(16) float xr_s[16][FSTR];
    __shared__ __align__(16) float lin_s[16][FSTR];
    layer_body(hswz, Wswz, bias_cat, att, bias, xout, hout,
               outW, outb, pos1, mode, N, blockIdx.x,
               xls_s, pes_s, xr_s, lin_s);
}

// ---------------------------------------------------------------------------
// interp: writes bf16 A-fragments for layer-2 GEMM directly.
// ---------------------------------------------------------------------------
__global__ __launch_bounds__(256)
void interp_kernel(const float* __restrict__ x0, const int* __restrict__ knn_idx,
                   const float* __restrict__ knn_w, unsigned short* __restrict__ hswz) {
    int wave = threadIdx.x >> 6;
    int lane = threadIdx.x & 63;
    int y = blockIdx.x * 4 + wave;
    int i0 = 2 * lane;
    float w0 = knn_w[y * 3], w1 = knn_w[y * 3 + 1], w2 = knn_w[y * 3 + 2];
    int j0 = knn_idx[y * 3], j1 = knn_idx[y * 3 + 1], j2 = knn_idx[y * 3 + 2];
    float inv = 1.0f / (w0 + w1 + w2);
    float2 a = *(const float2*)&x0[(size_t)j0 * 128 + i0];
    float2 b = *(const float2*)&x0[(size_t)j1 * 128 + i0];
    float2 c = *(const float2*)&x0[(size_t)j2 * 128 + i0];
    float rx = (w0 * a.x + w1 * b.x + w2 * c.x) * inv;
    float ry = (w0 * a.y + w1 * b.y + w2 * c.y) * inv;
    unsigned int packed = (unsigned int)f2bf(rx) | ((unsigned int)f2bf(ry) << 16);
    int g = i0 >> 5, sub = (i0 >> 3) & 3, jj = i0 & 7;
    size_t idx = (size_t)((((y >> 4) * 5 + g) * 64) + sub * 16 + (y & 15)) * 8 + jj;
    *(unsigned int*)&hswz[idx] = packed;
}

// ---------------------------------------------------------------------------
extern "C" void kernel_launch(void* const* d_in, const int* in_sizes, int n_in,
                              void* d_out, int out_size, void* d_ws, size_t ws_size,
                              hipStream_t stream) {
    (void)in_sizes; (void)n_in; (void)out_size; (void)ws_size;
    const float* latent   = (const float*)d_in[0];
    const float* pos0     = (const float*)d_in[1];
    const float* pos1     = (const float*)d_in[2];
    const float* conv_Wl  = (const float*)d_in[5];
    const float* conv_bl  = (const float*)d_in[6];
    const float* conv_Wr  = (const float*)d_in[7];
    const float* conv_br  = (const float*)d_in[8];
    const float* conv_We  = (const float*)d_in[9];
    const float* conv_att = (const float*)d_in[10];
    const float* conv_bias= (const float*)d_in[11];
    const float* lin0_W   = (const float*)d_in[12];
    const float* lin0_b   = (const float*)d_in[13];
    const float* lins_W   = (const float*)d_in[14];
    const float* lins_b   = (const float*)d_in[15];
    const float* out_W    = (const float*)d_in[16];
    const float* out_b    = (const float*)d_in[17];
    float* out = (float*)d_out;

    char* ws = (char*)d_ws;
    unsigned short* Wswz = (unsigned short*)ws; ws += (size_t)4 * WSWZ_PER_LAYER * 2;
    float* bias_cat = (float*)ws;  ws += (size_t)4 * JTOT * 4;
    float* Wt0      = (float*)ws;  ws += (size_t)64 * 128 * 4;
    unsigned short* hswz0A = (unsigned short*)ws; ws += (size_t)(N0 / 16) * NG * 64 * 8 * 2;
    unsigned short* hswz0B = (unsigned short*)ws; ws += (size_t)(N0 / 16) * NG * 64 * 8 * 2;
    unsigned short* hswz1A = (unsigned short*)ws; ws += (size_t)(N1 / 16) * NG * 64 * 8 * 2;
    unsigned short* hswz1B = (unsigned short*)ws; ws += (size_t)(N1 / 16) * NG * 64 * 8 * 2;
    float* bufA     = (float*)ws;  ws += (size_t)N0 * 128 * 4;
    float* pb_d     = (float*)ws;  ws += (size_t)KCH * N1 * 3 * 4;
    int*   pb_i     = (int*)ws;    ws += (size_t)KCH * N1 * 3 * 4;
    int*   knn_idx  = (int*)ws;    ws += (size_t)N1 * 3 * 4;
    float* knn_w    = (float*)ws;  ws += (size_t)N1 * 3 * 4;

    // A: knn_part (1024 blocks, first) || prep (3880 blocks)
    prep_knn_kernel<<<KNN_BLOCKS + PREP_BLOCKS, 256, 0, stream>>>(
        conv_Wl, conv_Wr, conv_We, lins_W, conv_bl, conv_br, lins_b, lin0_W,
        pos0, pos1, Wswz, bias_cat, Wt0, hswz0A, hswz0B, hswz1A, hswz1B,
        pb_d, pb_i);

    // B: knn_merge (128 blocks) || lin0 (4096 blocks)
    lin0_merge_kernel<<<MERGE_BLOCKS + N0, 128, 0, stream>>>(
        latent, Wt0, lin0_b, hswz0A, pb_d, pb_i, knn_idx, knn_w);

    // layer 0: h0A -> h0B (bf16 frags);  layer 1: h0B -> bufA (f32)
    fused_layer_kernel<<<N0 / 16, 512, 0, stream>>>(
        hswz0A, Wswz + (size_t)0 * WSWZ_PER_LAYER, bias_cat + 0 * JTOT,
        conv_att + 0 * 128, conv_bias + 0 * 128, nullptr, hswz0B,
        nullptr, nullptr, nullptr, 1, N0);
    fused_layer_kernel<<<N0 / 16, 512, 0, stream>>>(
        hswz0B, Wswz + (size_t)1 * WSWZ_PER_LAYER, bias_cat + 1 * JTOT,
        conv_att + 1 * 128, conv_bias + 1 * 128, bufA, nullptr,
        nullptr, nullptr, nullptr, 0, N0);

    interp_kernel<<<N1 / 4, 256, 0, stream>>>(bufA, knn_idx, knn_w, hswz1A);

    // layer 2: h1A -> h1B;  layer 3: h1B -> out (fused output head)
    fused_layer_kernel<<<N1 / 16, 512, 0, stream>>>(
        hswz1A, Wswz + (size_t)2 * WSWZ_PER_LAYER, bias_cat + 2 * JTOT,
        conv_att + 2 * 128, conv_bias + 2 * 128, nullptr, hswz1B,
        nullptr, nullptr, nullptr, 1, N1);
    fused_layer_kernel<<<N1 / 16, 512, 0, stream>>>(
        hswz1B, Wswz + (size_t)3 * WSWZ_PER_LAYER, bias_cat + 3 * JTOT,
        conv_att + 3 * 128, conv_bias + 3 * 128, out, nullptr,
        out_W, out_b, pos1, 2, N1);
}